// Round 4
// baseline (557.760 us; speedup 1.0000x reference)
//
#include <hip/hip_runtime.h>
#include <hip/hip_bf16.h>

#define IN_DIM 128
#define HID 256
#define BN_EPS 1e-5f

typedef __attribute__((ext_vector_type(8))) short bf16x8;
typedef __attribute__((ext_vector_type(16))) float f32x16;

// ---------- dtype helpers ----------
__device__ __forceinline__ float ld_f(const void* p, size_t i, int bf16) {
  if (bf16) return __bfloat162float(((const __hip_bfloat16*)p)[i]);
  return ((const float*)p)[i];
}
__device__ __forceinline__ float blo(unsigned u) { return __uint_as_float(u << 16); }
__device__ __forceinline__ float bhi(unsigned u) { return __uint_as_float(u & 0xffff0000u); }
__device__ __forceinline__ unsigned short f2bf(float f) {
  __hip_bfloat16 b = __float2bfloat16(f);
  return __builtin_bit_cast(unsigned short, b);
}

// flags[0] = 1 if float arrays are bf16, 0 if f32
// flags[1] = 1 if edge_index is int32, 0 if int64
__global__ void detect_kernel(const unsigned int* __restrict__ xw,
                              const unsigned int* __restrict__ eiw, int* flags) {
  __shared__ int votes, nz;
  if (threadIdx.x == 0) { votes = 0; nz = 0; }
  __syncthreads();
  int i = threadIdx.x;  // 256 threads
  unsigned int e = (xw[i] >> 7) & 0xFFu;
  int v = (e >= 100u && e <= 140u) ? 1 : 0;
  int z = (eiw[2 * i + 1] != 0u) ? 1 : 0;
  // wave-level reduce then LDS atomics
  atomicAdd(&votes, v);
  atomicAdd(&nz, z);
  __syncthreads();
  if (threadIdx.x == 0) {
    flags[0] = (votes > 128) ? 1 : 0;
    flags[1] = (nz > 0) ? 1 : 0;
  }
}

// convert indices + degree histogram (degf by dst, degb by src)
__global__ void convert_idx_kernel(const void* __restrict__ ei, const int* __restrict__ flags,
                                   int* __restrict__ src, int* __restrict__ dst,
                                   int* __restrict__ degf, int* __restrict__ degb, int n_edges) {
  int i = blockIdx.x * blockDim.x + threadIdx.x;
  if (i >= n_edges) return;
  int s, d;
  if (flags[1]) {
    s = ((const int*)ei)[i];
    d = ((const int*)ei)[n_edges + i];
  } else {
    s = (int)((const long long*)ei)[i];
    d = (int)((const long long*)ei)[n_edges + i];
  }
  src[i] = s;
  dst[i] = d;
  atomicAdd(&degf[d], 1);
  atomicAdd(&degb[s], 1);
}

// x -> bf16 self-slice of A1 (cols 256..383 of row-stride-384 matrix)
__global__ void convert_x_kernel(const void* __restrict__ x, const int* __restrict__ flags,
                                 __hip_bfloat16* __restrict__ A1, int n_nodes) {
  int bf = flags[0];
  size_t idx = (size_t)blockIdx.x * blockDim.x + threadIdx.x;
  size_t n = (size_t)n_nodes * IN_DIM;
  if (idx >= n) return;
  int row = (int)(idx >> 7), j = (int)(idx & 127);
  float v = ld_f(x, idx, bf);
  A1[(size_t)row * 384 + 256 + j] = __float2bfloat16(v);
}

// Pack weights into MFMA B-fragment order + fold biases.
// Wpk layout: element index ((t*STEPS + s)*64 + l)*8 + j  <->  W[k=s*16+(l>>5)*8+j][col=t*32+(l&31)]
__global__ void prep_params_kernel(
    const void* Wl_f1, const void* bl_f1, const void* Wr_f1,
    const void* Wl_b1, const void* bl_b1, const void* Wr_b1,
    const void* Wl_f2, const void* bl_f2, const void* Wr_f2,
    const void* Wl_b2, const void* bl_b2, const void* Wr_b2,
    const void* g1, const void* be1, const void* g2, const void* be2,
    const int* __restrict__ flags,
    __hip_bfloat16* __restrict__ Wpk1, float* __restrict__ b1,
    __hip_bfloat16* __restrict__ Wpk2, float* __restrict__ b2,
    float* __restrict__ gamma1, float* __restrict__ beta1,
    float* __restrict__ gamma2, float* __restrict__ beta2) {
  int bf = flags[0];
  int idx = blockIdx.x * blockDim.x + threadIdx.x;
  if (idx >= 768 * 256) return;
  {  // layer 2 pack (STEPS=48)
    int j = idx & 7, l = (idx >> 3) & 63, rest = idx >> 9;
    int s = rest % 48, t = rest / 48;
    int k = s * 16 + (l >> 5) * 8 + j, col = t * 32 + (l & 31);
    float v;
    if (k < 256)      v = ld_f(Wl_f2, (size_t)k * 256 + col, bf);
    else if (k < 512) v = ld_f(Wl_b2, (size_t)(k - 256) * 256 + col, bf);
    else              v = ld_f(Wr_f2, (size_t)(k - 512) * 256 + col, bf) +
                          ld_f(Wr_b2, (size_t)(k - 512) * 256 + col, bf);
    Wpk2[idx] = __float2bfloat16(v);
  }
  if (idx < 384 * 256) {  // layer 1 pack (STEPS=24)
    int j = idx & 7, l = (idx >> 3) & 63, rest = idx >> 9;
    int s = rest % 24, t = rest / 24;
    int k = s * 16 + (l >> 5) * 8 + j, col = t * 32 + (l & 31);
    float v;
    if (k < 128)      v = ld_f(Wl_f1, (size_t)k * 256 + col, bf);
    else if (k < 256) v = ld_f(Wl_b1, (size_t)(k - 128) * 256 + col, bf);
    else              v = ld_f(Wr_f1, (size_t)(k - 256) * 256 + col, bf) +
                          ld_f(Wr_b1, (size_t)(k - 256) * 256 + col, bf);
    Wpk1[idx] = __float2bfloat16(v);
  }
  if (idx < 256) {
    b1[idx] = ld_f(bl_f1, idx, bf) + ld_f(bl_b1, idx, bf);
    b2[idx] = ld_f(bl_f2, idx, bf) + ld_f(bl_b2, idx, bf);
    gamma1[idx] = ld_f(g1, idx, bf);
    beta1[idx]  = ld_f(be1, idx, bf);
    gamma2[idx] = ld_f(g2, idx, bf);
    beta2[idx]  = ld_f(be2, idx, bf);
  }
}

// ---------- CSR build ----------
__global__ void scan_part_kernel(const int* __restrict__ degf, const int* __restrict__ degb,
                                 int* __restrict__ offf, int* __restrict__ offb,
                                 int* __restrict__ partials, int n, int nb) {
  __shared__ int buf[256];
  const int b = blockIdx.x;
  const int* deg = (b < nb) ? degf : degb;
  int* off = (b < nb) ? offf : offb;
  const int chunk = (b < nb) ? b : (b - nb);
  const int i = chunk * 256 + threadIdx.x;
  int v = (i < n) ? deg[i] : 0;
  buf[threadIdx.x] = v;
  __syncthreads();
  for (int s = 1; s < 256; s <<= 1) {
    int t = (threadIdx.x >= s) ? buf[threadIdx.x - s] : 0;
    __syncthreads();
    buf[threadIdx.x] += t;
    __syncthreads();
  }
  if (i < n) off[i] = buf[threadIdx.x] - v;
  if (threadIdx.x == 255) partials[b] = buf[255];
}

__global__ void scan_partials_kernel(int* __restrict__ partials, int nb) {
  __shared__ int buf[256];
  for (int a = 0; a < 2; ++a) {
    int v = (threadIdx.x < nb) ? partials[a * nb + threadIdx.x] : 0;
    buf[threadIdx.x] = v;
    __syncthreads();
    for (int s = 1; s < 256; s <<= 1) {
      int t = (threadIdx.x >= s) ? buf[threadIdx.x - s] : 0;
      __syncthreads();
      buf[threadIdx.x] += t;
      __syncthreads();
    }
    if (threadIdx.x < nb) partials[a * nb + threadIdx.x] = buf[threadIdx.x] - v;
    __syncthreads();
  }
}

__global__ void scan_add_kernel(int* __restrict__ offf, int* __restrict__ offb,
                                int* __restrict__ curf, int* __restrict__ curb,
                                const int* __restrict__ partials, int n, int nb, int n_edges) {
  const int b = blockIdx.x;
  int* off = (b < nb) ? offf : offb;
  int* cur = (b < nb) ? curf : curb;
  const int chunk = (b < nb) ? b : (b - nb);
  const int i = chunk * 256 + threadIdx.x;
  if (i < n) {
    int v = off[i] + partials[b];
    off[i] = v;
    cur[i] = v;
  }
  if (b == 0 && threadIdx.x == 0) { offf[n] = n_edges; offb[n] = n_edges; }
}

__global__ void fill_adj_kernel(const int* __restrict__ src, const int* __restrict__ dst,
                                int* __restrict__ curf, int* __restrict__ curb,
                                int* __restrict__ adjf, int* __restrict__ adjb, int n_edges) {
  int i = blockIdx.x * blockDim.x + threadIdx.x;
  if (i >= n_edges) return;
  int s = src[i], d = dst[i];
  adjf[atomicAdd(&curf[d], 1)] = s;
  adjb[atomicAdd(&curb[s], 1)] = d;
}

// ---------- gather-mean (bf16 in, bf16 out), multi-neighbor per wave ----------
template <int D>
__global__ __launch_bounds__(256) void gather_mean_kernel(
    __hip_bfloat16* __restrict__ A,
    const int* __restrict__ adjf, const int* __restrict__ offf,
    const int* __restrict__ adjb, const int* __restrict__ offb, int n_nodes) {
  constexpr int LPN = D / 8;     // lanes per neighbor row (16B = 8 bf16 each)
  constexpr int NPI = 64 / LPN;  // neighbors per iteration
  const int gw = (int)(((size_t)blockIdx.x * 256 + threadIdx.x) >> 6);
  const int lane = threadIdx.x & 63;
  if (gw >= 2 * n_nodes) return;
  int node, dir;
  const int *adj, *off;
  if (gw < n_nodes) { node = gw;           adj = adjf; off = offf; dir = 0; }
  else              { node = gw - n_nodes; adj = adjb; off = offb; dir = 1; }
  const int s = off[node], e = off[node + 1];
  const int sub = lane / LPN, cl = lane % LPN;
  float acc[8] = {0.f, 0.f, 0.f, 0.f, 0.f, 0.f, 0.f, 0.f};
  for (int i = s; i < e; i += NPI) {
    const int idx = i + sub;
    if (idx < e) {
      const int nb = adj[idx];
      const uint4 w = *(const uint4*)(A + (size_t)nb * (3 * D) + 2 * D + cl * 8);
      acc[0] += blo(w.x); acc[1] += bhi(w.x);
      acc[2] += blo(w.y); acc[3] += bhi(w.y);
      acc[4] += blo(w.z); acc[5] += bhi(w.z);
      acc[6] += blo(w.w); acc[7] += bhi(w.w);
    }
  }
#pragma unroll
  for (int o = 32; o >= LPN; o >>= 1) {
#pragma unroll
    for (int k = 0; k < 8; ++k) acc[k] += __shfl_xor(acc[k], o, 64);
  }
  if (sub == 0) {
    const float inv = 1.0f / (float)max(e - s, 1);
    union { unsigned short us[8]; uint4 v; } o;
#pragma unroll
    for (int k = 0; k < 8; ++k) o.us[k] = f2bf(acc[k] * inv);
    *(uint4*)(A + (size_t)node * (3 * D) + dir * D + cl * 8) = o.v;
  }
}

// ---------- MFMA GEMM v2: block = 32 rows x 256 cols, 4 waves x 64 cols ----------
// Depth-1 register prefetch of A (HBM) and W (L2) keeps ~3KB/wave in flight.
template <int K>
__global__ __launch_bounds__(256) void gemm_mfma_kernel(
    const __hip_bfloat16* __restrict__ A, const __hip_bfloat16* __restrict__ Wpk,
    const float* __restrict__ bias, float* __restrict__ C,
    float* __restrict__ bnsum, float* __restrict__ bnsum2, int M) {
  constexpr int STEPS = K / 16;
  __shared__ float colsum[256], colsum2[256];
  colsum[threadIdx.x] = 0.f;
  colsum2[threadIdx.x] = 0.f;
  __syncthreads();
  const int wave = threadIdx.x >> 6, lane = threadIdx.x & 63;
  const int rbase = blockIdx.x * 32;
  const int tg0 = wave * 2;  // first 32-col group of this wave
  const __hip_bfloat16* aptr = A + (size_t)(rbase + (lane & 31)) * K + (lane >> 5) * 8;
  const __hip_bfloat16* w0p = Wpk + ((size_t)(tg0 * STEPS) * 64 + lane) * 8;
  const __hip_bfloat16* w1p = Wpk + ((size_t)((tg0 + 1) * STEPS) * 64 + lane) * 8;
  f32x16 acc0 = {}, acc1 = {};
  bf16x8 a_c = *(const bf16x8*)aptr;
  bf16x8 w0_c = *(const bf16x8*)w0p;
  bf16x8 w1_c = *(const bf16x8*)w1p;
  for (int s = 0; s < STEPS - 1; ++s) {
    aptr += 16; w0p += 512; w1p += 512;
    bf16x8 a_n = *(const bf16x8*)aptr;       // prefetch (overread at loop end is
    bf16x8 w0_n = *(const bf16x8*)w0p;       //  within the workspace; unused)
    bf16x8 w1_n = *(const bf16x8*)w1p;
    acc0 = __builtin_amdgcn_mfma_f32_32x32x16_bf16(a_c, w0_c, acc0, 0, 0, 0);
    acc1 = __builtin_amdgcn_mfma_f32_32x32x16_bf16(a_c, w1_c, acc1, 0, 0, 0);
    a_c = a_n; w0_c = w0_n; w1_c = w1_n;
  }
  acc0 = __builtin_amdgcn_mfma_f32_32x32x16_bf16(a_c, w0_c, acc0, 0, 0, 0);
  acc1 = __builtin_amdgcn_mfma_f32_32x32x16_bf16(a_c, w1_c, acc1, 0, 0, 0);
  f32x16 accs[2] = {acc0, acc1};
#pragma unroll
  for (int t = 0; t < 2; ++t) {
    const int col = (tg0 + t) * 32 + (lane & 31);
    const float bj = bias[col];
    float ls = 0.f, ls2 = 0.f;
#pragma unroll
    for (int r = 0; r < 16; ++r) {
      const int row = rbase + (r & 3) + 8 * (r >> 2) + 4 * (lane >> 5);
      if (row < M) {
        float v = accs[t][r] + bj;
        C[(size_t)row * 256 + col] = v;
        ls += v;
        ls2 = fmaf(v, v, ls2);
      }
    }
    atomicAdd(&colsum[col], ls);
    atomicAdd(&colsum2[col], ls2);
  }
  __syncthreads();
  atomicAdd(&bnsum[threadIdx.x], colsum[threadIdx.x]);
  atomicAdd(&bnsum2[threadIdx.x], colsum2[threadIdx.x]);
}

// ---------- BN ----------
__global__ void bn_finalize_kernel(const float* __restrict__ sum, const float* __restrict__ sumsq,
                                   float* __restrict__ musig, float n) {
  int j = threadIdx.x;
  float mu = sum[j] / n;
  float var = fmaxf(sumsq[j] / n - mu * mu, 0.f);
  musig[j] = mu;
  musig[j + 256] = rsqrtf(var + BN_EPS);
}

// BN+ReLU h1 -> bf16 self-slice of A2 (cols 512..767, row stride 768); one block per row
__global__ void bn_apply_bf16_kernel(const float* __restrict__ hpre, const float* __restrict__ musig,
                                     const float* __restrict__ gamma, const float* __restrict__ beta,
                                     __hip_bfloat16* __restrict__ A2) {
  int j = threadIdx.x;
  int row = blockIdx.x;
  float v = hpre[(size_t)row * 256 + j];
  v = fmaxf(fmaf(gamma[j] * (v - musig[j]), musig[j + 256], beta[j]), 0.f);
  A2[(size_t)row * 768 + 512 + j] = __float2bfloat16(v);
}

__global__ void bn_apply_max_kernel(const float* __restrict__ h, const float* __restrict__ musig,
                                    const float* __restrict__ gamma, const float* __restrict__ beta,
                                    int n_nodes, float* __restrict__ out_tmp) {
  int j = threadIdx.x;
  float mu = musig[j], rs = musig[j + 256], g = gamma[j], be = beta[j];
  float m = 0.f;  // ReLU output >= 0
  for (int n = blockIdx.x; n < n_nodes; n += gridDim.x) {
    float v = h[(size_t)n * HID + j];
    v = fmaxf(fmaf(g * (v - mu), rs, be), 0.f);
    m = fmaxf(m, v);
  }
  atomicMax((int*)&out_tmp[j], __float_as_int(m));
}

__global__ void write_out_kernel(const float* __restrict__ out_tmp, const int* __restrict__ flags,
                                 void* __restrict__ out, int out_size) {
  int j = threadIdx.x;
  if (j >= out_size) return;
  float v = out_tmp[j];
  if (flags[0]) ((__hip_bfloat16*)out)[j] = __float2bfloat16(v);
  else          ((float*)out)[j] = v;
}

extern "C" void kernel_launch(void* const* d_in, const int* in_sizes, int n_in,
                              void* d_out, int out_size, void* d_ws, size_t ws_size,
                              hipStream_t stream) {
  const void* x  = d_in[0];
  const void* ei = d_in[1];
  const int n_nodes = in_sizes[0] / IN_DIM;
  const int n_edges = in_sizes[1] / 2;
  const int nb = (n_nodes + 255) / 256;
  const int Mpad = (n_nodes + 31) & ~31;

  float* ws = (float*)d_ws;
  size_t off = 0;
  auto alloc = [&](size_t n) {
    float* p = ws + off;
    off += (n + 1023) & ~(size_t)1023;
    return p;
  };
  int*   flags   = (int*)alloc(1024);
  __hip_bfloat16* Wpk1 = (__hip_bfloat16*)alloc(384 * 256 / 2);
  __hip_bfloat16* Wpk2 = (__hip_bfloat16*)alloc(768 * 256 / 2);
  float* b1      = alloc(256);
  float* b2      = alloc(256);
  float* gamma1  = alloc(256);
  float* beta1   = alloc(256);
  float* gamma2  = alloc(256);
  float* beta2   = alloc(256);
  float* sum1    = alloc(256);
  float* sumsq1  = alloc(256);
  float* musig1  = alloc(512);
  float* sum2    = alloc(256);
  float* sumsq2  = alloc(256);
  float* musig2  = alloc(512);
  float* out_tmp = alloc(256);
  int*   srcI    = (int*)alloc(n_edges);
  int*   dstI    = (int*)alloc(n_edges);
  int*   degf    = (int*)alloc(n_nodes);
  int*   degb    = (int*)alloc(n_nodes);
  int*   offf    = (int*)alloc(n_nodes + 1);
  int*   offb    = (int*)alloc(n_nodes + 1);
  int*   curf    = (int*)alloc(n_nodes);
  int*   curb    = (int*)alloc(n_nodes);
  int*   adjf    = (int*)alloc(n_edges);
  int*   adjb    = (int*)alloc(n_edges);
  int*   partials = (int*)alloc(2 * nb);
  __hip_bfloat16* A1 = (__hip_bfloat16*)alloc((size_t)Mpad * 384 / 2);
  __hip_bfloat16* A2 = (__hip_bfloat16*)alloc((size_t)Mpad * 768 / 2);
  float* hpre    = alloc((size_t)n_nodes * HID);  // shared by layer 1 & 2
  (void)ws_size; (void)n_in;

  hipMemsetAsync(degf, 0, (size_t)n_nodes * 4, stream);
  hipMemsetAsync(degb, 0, (size_t)n_nodes * 4, stream);
  hipMemsetAsync(sum1, 0, 256 * 4, stream);
  hipMemsetAsync(sumsq1, 0, 256 * 4, stream);
  hipMemsetAsync(sum2, 0, 256 * 4, stream);
  hipMemsetAsync(sumsq2, 0, 256 * 4, stream);
  hipMemsetAsync(out_tmp, 0, 256 * 4, stream);

  detect_kernel<<<1, 256, 0, stream>>>((const unsigned int*)x, (const unsigned int*)ei, flags);
  convert_idx_kernel<<<(n_edges + 255) / 256, 256, 0, stream>>>(ei, flags, srcI, dstI, degf, degb, n_edges);
  convert_x_kernel<<<(n_nodes * IN_DIM + 255) / 256, 256, 0, stream>>>(x, flags, A1, n_nodes);
  prep_params_kernel<<<768, 256, 0, stream>>>(
      d_in[2], d_in[3], d_in[4], d_in[5], d_in[6], d_in[7],
      d_in[8], d_in[9], d_in[10], d_in[11], d_in[12], d_in[13],
      d_in[14], d_in[15], d_in[16], d_in[17],
      flags, Wpk1, b1, Wpk2, b2, gamma1, beta1, gamma2, beta2);

  scan_part_kernel<<<2 * nb, 256, 0, stream>>>(degf, degb, offf, offb, partials, n_nodes, nb);
  scan_partials_kernel<<<1, 256, 0, stream>>>(partials, nb);
  scan_add_kernel<<<2 * nb, 256, 0, stream>>>(offf, offb, curf, curb, partials, n_nodes, nb, n_edges);
  fill_adj_kernel<<<(n_edges + 255) / 256, 256, 0, stream>>>(srcI, dstI, curf, curb, adjf, adjb, n_edges);

  // ---- layer 1 ----
  gather_mean_kernel<IN_DIM><<<(2 * n_nodes + 3) / 4, 256, 0, stream>>>(
      A1, adjf, offf, adjb, offb, n_nodes);
  gemm_mfma_kernel<384><<<Mpad / 32, 256, 0, stream>>>(
      A1, Wpk1, b1, hpre, sum1, sumsq1, n_nodes);
  bn_finalize_kernel<<<1, 256, 0, stream>>>(sum1, sumsq1, musig1, (float)n_nodes);
  bn_apply_bf16_kernel<<<n_nodes, 256, 0, stream>>>(hpre, musig1, gamma1, beta1, A2);

  // ---- layer 2 ----
  gather_mean_kernel<HID><<<(2 * n_nodes + 3) / 4, 256, 0, stream>>>(
      A2, adjf, offf, adjb, offb, n_nodes);
  gemm_mfma_kernel<768><<<Mpad / 32, 256, 0, stream>>>(
      A2, Wpk2, b2, hpre, sum2, sumsq2, n_nodes);
  bn_finalize_kernel<<<1, 256, 0, stream>>>(sum2, sumsq2, musig2, (float)n_nodes);
  bn_apply_max_kernel<<<1024, 256, 0, stream>>>(hpre, musig2, gamma2, beta2, n_nodes, out_tmp);
  write_out_kernel<<<1, 256, 0, stream>>>(out_tmp, flags, d_out, out_size);
}

// Round 5
// 517.851 us; speedup vs baseline: 1.0771x; 1.0771x over previous
//
#include <hip/hip_runtime.h>
#include <hip/hip_bf16.h>

#define IN_DIM 128
#define HID 256
#define BN_EPS 1e-5f

typedef __attribute__((ext_vector_type(8))) short bf16x8;
typedef __attribute__((ext_vector_type(16))) float f32x16;

// ---------- dtype helpers ----------
__device__ __forceinline__ float ld_f(const void* p, size_t i, int bf16) {
  if (bf16) return __bfloat162float(((const __hip_bfloat16*)p)[i]);
  return ((const float*)p)[i];
}
__device__ __forceinline__ float blo(unsigned u) { return __uint_as_float(u << 16); }
__device__ __forceinline__ float bhi(unsigned u) { return __uint_as_float(u & 0xffff0000u); }
__device__ __forceinline__ unsigned short f2bf(float f) {
  __hip_bfloat16 b = __float2bfloat16(f);
  return __builtin_bit_cast(unsigned short, b);
}

// flags[0] = 1 if float arrays are bf16, 0 if f32
// flags[1] = 1 if edge_index is int32, 0 if int64
__global__ void detect_kernel(const unsigned int* __restrict__ xw,
                              const unsigned int* __restrict__ eiw, int* flags) {
  __shared__ int votes, nz;
  if (threadIdx.x == 0) { votes = 0; nz = 0; }
  __syncthreads();
  int i = threadIdx.x;  // 256 threads
  unsigned int e = (xw[i] >> 7) & 0xFFu;
  int v = (e >= 100u && e <= 140u) ? 1 : 0;
  int z = (eiw[2 * i + 1] != 0u) ? 1 : 0;
  atomicAdd(&votes, v);
  atomicAdd(&nz, z);
  __syncthreads();
  if (threadIdx.x == 0) {
    flags[0] = (votes > 128) ? 1 : 0;
    flags[1] = (nz > 0) ? 1 : 0;
  }
}

// convert indices + degree histogram (degf by dst, degb by src)
__global__ void convert_idx_kernel(const void* __restrict__ ei, const int* __restrict__ flags,
                                   int* __restrict__ src, int* __restrict__ dst,
                                   int* __restrict__ degf, int* __restrict__ degb, int n_edges) {
  int i = blockIdx.x * blockDim.x + threadIdx.x;
  if (i >= n_edges) return;
  int s, d;
  if (flags[1]) {
    s = ((const int*)ei)[i];
    d = ((const int*)ei)[n_edges + i];
  } else {
    s = (int)((const long long*)ei)[i];
    d = (int)((const long long*)ei)[n_edges + i];
  }
  src[i] = s;
  dst[i] = d;
  atomicAdd(&degf[d], 1);
  atomicAdd(&degb[s], 1);
}

// x -> bf16 self-slice of A1 (cols 256..383 of row-stride-384 matrix)
__global__ void convert_x_kernel(const void* __restrict__ x, const int* __restrict__ flags,
                                 __hip_bfloat16* __restrict__ A1, int n_nodes) {
  int bf = flags[0];
  size_t idx = (size_t)blockIdx.x * blockDim.x + threadIdx.x;
  size_t n = (size_t)n_nodes * IN_DIM;
  if (idx >= n) return;
  int row = (int)(idx >> 7), j = (int)(idx & 127);
  float v = ld_f(x, idx, bf);
  A1[(size_t)row * 384 + 256 + j] = __float2bfloat16(v);
}

// Pack weights into MFMA B-fragment order + fold biases.
// Wpk layout: element index ((t*STEPS + s)*64 + l)*8 + j  <->  W[k=s*16+(l>>5)*8+j][col=t*32+(l&31)]
__global__ void prep_params_kernel(
    const void* Wl_f1, const void* bl_f1, const void* Wr_f1,
    const void* Wl_b1, const void* bl_b1, const void* Wr_b1,
    const void* Wl_f2, const void* bl_f2, const void* Wr_f2,
    const void* Wl_b2, const void* bl_b2, const void* Wr_b2,
    const void* g1, const void* be1, const void* g2, const void* be2,
    const int* __restrict__ flags,
    __hip_bfloat16* __restrict__ Wpk1, float* __restrict__ b1,
    __hip_bfloat16* __restrict__ Wpk2, float* __restrict__ b2,
    float* __restrict__ gamma1, float* __restrict__ beta1,
    float* __restrict__ gamma2, float* __restrict__ beta2) {
  int bf = flags[0];
  int idx = blockIdx.x * blockDim.x + threadIdx.x;
  if (idx >= 768 * 256) return;
  {  // layer 2 pack (STEPS=48)
    int j = idx & 7, l = (idx >> 3) & 63, rest = idx >> 9;
    int s = rest % 48, t = rest / 48;
    int k = s * 16 + (l >> 5) * 8 + j, col = t * 32 + (l & 31);
    float v;
    if (k < 256)      v = ld_f(Wl_f2, (size_t)k * 256 + col, bf);
    else if (k < 512) v = ld_f(Wl_b2, (size_t)(k - 256) * 256 + col, bf);
    else              v = ld_f(Wr_f2, (size_t)(k - 512) * 256 + col, bf) +
                          ld_f(Wr_b2, (size_t)(k - 512) * 256 + col, bf);
    Wpk2[idx] = __float2bfloat16(v);
  }
  if (idx < 384 * 256) {  // layer 1 pack (STEPS=24)
    int j = idx & 7, l = (idx >> 3) & 63, rest = idx >> 9;
    int s = rest % 24, t = rest / 24;
    int k = s * 16 + (l >> 5) * 8 + j, col = t * 32 + (l & 31);
    float v;
    if (k < 128)      v = ld_f(Wl_f1, (size_t)k * 256 + col, bf);
    else if (k < 256) v = ld_f(Wl_b1, (size_t)(k - 128) * 256 + col, bf);
    else              v = ld_f(Wr_f1, (size_t)(k - 256) * 256 + col, bf) +
                          ld_f(Wr_b1, (size_t)(k - 256) * 256 + col, bf);
    Wpk1[idx] = __float2bfloat16(v);
  }
  if (idx < 256) {
    b1[idx] = ld_f(bl_f1, idx, bf) + ld_f(bl_b1, idx, bf);
    b2[idx] = ld_f(bl_f2, idx, bf) + ld_f(bl_b2, idx, bf);
    gamma1[idx] = ld_f(g1, idx, bf);
    beta1[idx]  = ld_f(be1, idx, bf);
    gamma2[idx] = ld_f(g2, idx, bf);
    beta2[idx]  = ld_f(be2, idx, bf);
  }
}

// ---------- CSR build ----------
__global__ void scan_part_kernel(const int* __restrict__ degf, const int* __restrict__ degb,
                                 int* __restrict__ offf, int* __restrict__ offb,
                                 int* __restrict__ partials, int n, int nb) {
  __shared__ int buf[256];
  const int b = blockIdx.x;
  const int* deg = (b < nb) ? degf : degb;
  int* off = (b < nb) ? offf : offb;
  const int chunk = (b < nb) ? b : (b - nb);
  const int i = chunk * 256 + threadIdx.x;
  int v = (i < n) ? deg[i] : 0;
  buf[threadIdx.x] = v;
  __syncthreads();
  for (int s = 1; s < 256; s <<= 1) {
    int t = (threadIdx.x >= s) ? buf[threadIdx.x - s] : 0;
    __syncthreads();
    buf[threadIdx.x] += t;
    __syncthreads();
  }
  if (i < n) off[i] = buf[threadIdx.x] - v;
  if (threadIdx.x == 255) partials[b] = buf[255];
}

__global__ void scan_partials_kernel(int* __restrict__ partials, int nb) {
  __shared__ int buf[256];
  for (int a = 0; a < 2; ++a) {
    int v = (threadIdx.x < nb) ? partials[a * nb + threadIdx.x] : 0;
    buf[threadIdx.x] = v;
    __syncthreads();
    for (int s = 1; s < 256; s <<= 1) {
      int t = (threadIdx.x >= s) ? buf[threadIdx.x - s] : 0;
      __syncthreads();
      buf[threadIdx.x] += t;
      __syncthreads();
    }
    if (threadIdx.x < nb) partials[a * nb + threadIdx.x] = buf[threadIdx.x] - v;
    __syncthreads();
  }
}

__global__ void scan_add_kernel(int* __restrict__ offf, int* __restrict__ offb,
                                int* __restrict__ curf, int* __restrict__ curb,
                                const int* __restrict__ partials, int n, int nb, int n_edges) {
  const int b = blockIdx.x;
  int* off = (b < nb) ? offf : offb;
  int* cur = (b < nb) ? curf : curb;
  const int chunk = (b < nb) ? b : (b - nb);
  const int i = chunk * 256 + threadIdx.x;
  if (i < n) {
    int v = off[i] + partials[b];
    off[i] = v;
    cur[i] = v;
  }
  if (b == 0 && threadIdx.x == 0) { offf[n] = n_edges; offb[n] = n_edges; }
}

__global__ void fill_adj_kernel(const int* __restrict__ src, const int* __restrict__ dst,
                                int* __restrict__ curf, int* __restrict__ curb,
                                int* __restrict__ adjf, int* __restrict__ adjb, int n_edges) {
  int i = blockIdx.x * blockDim.x + threadIdx.x;
  if (i >= n_edges) return;
  int s = src[i], d = dst[i];
  adjf[atomicAdd(&curf[d], 1)] = s;
  adjb[atomicAdd(&curb[s], 1)] = d;
}

// ---------- gather-mean v2: depth-2 pipelined row loads, branchless clamped idx ----------
template <int D>
__global__ __launch_bounds__(256) void gather_mean_kernel(
    __hip_bfloat16* __restrict__ A,
    const int* __restrict__ adjf, const int* __restrict__ offf,
    const int* __restrict__ adjb, const int* __restrict__ offb, int n_nodes) {
  constexpr int LPN = D / 8;     // lanes per neighbor row (16B = 8 bf16 each)
  constexpr int NPI = 64 / LPN;  // neighbors per iteration
  const int gw = (int)(((size_t)blockIdx.x * 256 + threadIdx.x) >> 6);
  const int lane = threadIdx.x & 63;
  if (gw >= 2 * n_nodes) return;
  int node, dir;
  const int *adj, *off;
  if (gw < n_nodes) { node = gw;           adj = adjf; off = offf; dir = 0; }
  else              { node = gw - n_nodes; adj = adjb; off = offb; dir = 1; }
  const int s = off[node], e = off[node + 1];
  const int sub = lane / LPN, cl = lane % LPN;
  const size_t coloff = 2 * (size_t)D + cl * 8;  // self-slice column offset
  auto clampi = [&](int i) { return max(min(i, e - 1), 0); };
  float acc[8] = {0.f, 0.f, 0.f, 0.f, 0.f, 0.f, 0.f, 0.f};
  int i = s + sub;
  int a0 = adj[clampi(i)];
  int a1 = adj[clampi(i + NPI)];
  uint4 r0 = *(const uint4*)(A + (size_t)a0 * (3 * D) + coloff);
  for (; i < e; i += NPI) {
    const uint4 r1 = *(const uint4*)(A + (size_t)a1 * (3 * D) + coloff);  // next row, in flight
    const int a2 = adj[clampi(i + 2 * NPI)];
    acc[0] += blo(r0.x); acc[1] += bhi(r0.x);
    acc[2] += blo(r0.y); acc[3] += bhi(r0.y);
    acc[4] += blo(r0.z); acc[5] += bhi(r0.z);
    acc[6] += blo(r0.w); acc[7] += bhi(r0.w);
    r0 = r1; a1 = a2;
  }
#pragma unroll
  for (int o = 32; o >= LPN; o >>= 1) {
#pragma unroll
    for (int k = 0; k < 8; ++k) acc[k] += __shfl_xor(acc[k], o, 64);
  }
  if (sub == 0) {
    const float inv = 1.0f / (float)max(e - s, 1);
    union { unsigned short us[8]; uint4 v; } o;
#pragma unroll
    for (int k = 0; k < 8; ++k) o.us[k] = f2bf(acc[k] * inv);
    *(uint4*)(A + (size_t)node * (3 * D) + dir * D + cl * 8) = o.v;
  }
}

// ---------- MFMA GEMM v3: block = 64 rows x 256 cols, wave = 32 rows x 128 cols ----------
// 4 C-frags/wave (4 MFMAs/step) + depth-2 double-buffered register prefetch.
template <int K>
__global__ __launch_bounds__(256) void gemm_mfma_kernel(
    const __hip_bfloat16* __restrict__ A, const __hip_bfloat16* __restrict__ Wpk,
    const float* __restrict__ bias, float* __restrict__ C,
    float* __restrict__ bnsum, float* __restrict__ bnsum2, int M) {
  constexpr int STEPS = K / 16;
  __shared__ float colsum[256], colsum2[256];
  colsum[threadIdx.x] = 0.f;
  colsum2[threadIdx.x] = 0.f;
  __syncthreads();
  const int wave = threadIdx.x >> 6, lane = threadIdx.x & 63;
  const int rg = wave & 1, cg = wave >> 1;
  const int rbase = blockIdx.x * 64 + rg * 32;
  const int cbase = cg * 128;
  const __hip_bfloat16* aptr = A + (size_t)(rbase + (lane & 31)) * K + (lane >> 5) * 8;
  const __hip_bfloat16* wptr = Wpk + ((size_t)(cg * 4) * STEPS * 64 + lane) * 8;
  constexpr size_t WT = (size_t)1 * 64 * 8;  // 512 elems per k-step per col group

  bf16x8 aB[2];
  bf16x8 wB[2][4];
  aB[0] = *(const bf16x8*)aptr;
  aB[1] = *(const bf16x8*)(aptr + 16);
#pragma unroll
  for (int t = 0; t < 4; ++t) {
    wB[0][t] = *(const bf16x8*)(wptr + (size_t)t * STEPS * WT);
    wB[1][t] = *(const bf16x8*)(wptr + (size_t)t * STEPS * WT + WT);
  }
  f32x16 acc0 = {}, acc1 = {}, acc2 = {}, acc3 = {};
#pragma unroll
  for (int s = 0; s < STEPS; ++s) {
    const int p = s & 1;
    const bf16x8 a = aB[p];
    const bf16x8 w0 = wB[p][0], w1 = wB[p][1], w2 = wB[p][2], w3 = wB[p][3];
    if (s + 2 < STEPS) {  // re-fill this slot for step s+2 (static after unroll)
      aB[p] = *(const bf16x8*)(aptr + (size_t)(s + 2) * 16);
#pragma unroll
      for (int t = 0; t < 4; ++t)
        wB[p][t] = *(const bf16x8*)(wptr + (size_t)t * STEPS * WT + (size_t)(s + 2) * WT);
    }
    acc0 = __builtin_amdgcn_mfma_f32_32x32x16_bf16(a, w0, acc0, 0, 0, 0);
    acc1 = __builtin_amdgcn_mfma_f32_32x32x16_bf16(a, w1, acc1, 0, 0, 0);
    acc2 = __builtin_amdgcn_mfma_f32_32x32x16_bf16(a, w2, acc2, 0, 0, 0);
    acc3 = __builtin_amdgcn_mfma_f32_32x32x16_bf16(a, w3, acc3, 0, 0, 0);
  }
  f32x16 accs[4] = {acc0, acc1, acc2, acc3};
#pragma unroll
  for (int t = 0; t < 4; ++t) {
    const int col = cbase + t * 32 + (lane & 31);
    const float bj = bias[col];
    float ls = 0.f, ls2 = 0.f;
#pragma unroll
    for (int r = 0; r < 16; ++r) {
      const int row = rbase + (r & 3) + 8 * (r >> 2) + 4 * (lane >> 5);
      if (row < M) {
        float v = accs[t][r] + bj;
        C[(size_t)row * 256 + col] = v;
        ls += v;
        ls2 = fmaf(v, v, ls2);
      }
    }
    atomicAdd(&colsum[col], ls);
    atomicAdd(&colsum2[col], ls2);
  }
  __syncthreads();
  atomicAdd(&bnsum[threadIdx.x], colsum[threadIdx.x]);
  atomicAdd(&bnsum2[threadIdx.x], colsum2[threadIdx.x]);
}

// ---------- BN ----------
__global__ void bn_finalize_kernel(const float* __restrict__ sum, const float* __restrict__ sumsq,
                                   float* __restrict__ musig, float n) {
  int j = threadIdx.x;
  float mu = sum[j] / n;
  float var = fmaxf(sumsq[j] / n - mu * mu, 0.f);
  musig[j] = mu;
  musig[j + 256] = rsqrtf(var + BN_EPS);
}

// BN+ReLU h1 -> bf16 self-slice of A2 (cols 512..767, row stride 768); one block per row
__global__ void bn_apply_bf16_kernel(const float* __restrict__ hpre, const float* __restrict__ musig,
                                     const float* __restrict__ gamma, const float* __restrict__ beta,
                                     __hip_bfloat16* __restrict__ A2) {
  int j = threadIdx.x;
  int row = blockIdx.x;
  float v = hpre[(size_t)row * 256 + j];
  v = fmaxf(fmaf(gamma[j] * (v - musig[j]), musig[j + 256], beta[j]), 0.f);
  A2[(size_t)row * 768 + 512 + j] = __float2bfloat16(v);
}

__global__ void bn_apply_max_kernel(const float* __restrict__ h, const float* __restrict__ musig,
                                    const float* __restrict__ gamma, const float* __restrict__ beta,
                                    int n_nodes, float* __restrict__ out_tmp) {
  int j = threadIdx.x;
  float mu = musig[j], rs = musig[j + 256], g = gamma[j], be = beta[j];
  float m = 0.f;  // ReLU output >= 0
  for (int n = blockIdx.x; n < n_nodes; n += gridDim.x) {
    float v = h[(size_t)n * HID + j];
    v = fmaxf(fmaf(g * (v - mu), rs, be), 0.f);
    m = fmaxf(m, v);
  }
  atomicMax((int*)&out_tmp[j], __float_as_int(m));
}

__global__ void write_out_kernel(const float* __restrict__ out_tmp, const int* __restrict__ flags,
                                 void* __restrict__ out, int out_size) {
  int j = threadIdx.x;
  if (j >= out_size) return;
  float v = out_tmp[j];
  if (flags[0]) ((__hip_bfloat16*)out)[j] = __float2bfloat16(v);
  else          ((float*)out)[j] = v;
}

extern "C" void kernel_launch(void* const* d_in, const int* in_sizes, int n_in,
                              void* d_out, int out_size, void* d_ws, size_t ws_size,
                              hipStream_t stream) {
  const void* x  = d_in[0];
  const void* ei = d_in[1];
  const int n_nodes = in_sizes[0] / IN_DIM;
  const int n_edges = in_sizes[1] / 2;
  const int nb = (n_nodes + 255) / 256;
  const int Mpad = (n_nodes + 63) & ~63;

  float* ws = (float*)d_ws;
  size_t off = 0;
  auto alloc = [&](size_t n) {
    float* p = ws + off;
    off += (n + 1023) & ~(size_t)1023;
    return p;
  };
  int*   flags   = (int*)alloc(1024);
  __hip_bfloat16* Wpk1 = (__hip_bfloat16*)alloc(384 * 256 / 2);
  __hip_bfloat16* Wpk2 = (__hip_bfloat16*)alloc(768 * 256 / 2);
  float* b1      = alloc(256);
  float* b2      = alloc(256);
  float* gamma1  = alloc(256);
  float* beta1   = alloc(256);
  float* gamma2  = alloc(256);
  float* beta2   = alloc(256);
  float* sum1    = alloc(256);
  float* sumsq1  = alloc(256);
  float* musig1  = alloc(512);
  float* sum2    = alloc(256);
  float* sumsq2  = alloc(256);
  float* musig2  = alloc(512);
  float* out_tmp = alloc(256);
  int*   srcI    = (int*)alloc(n_edges);
  int*   dstI    = (int*)alloc(n_edges);
  int*   degf    = (int*)alloc(n_nodes);
  int*   degb    = (int*)alloc(n_nodes);
  int*   offf    = (int*)alloc(n_nodes + 1);
  int*   offb    = (int*)alloc(n_nodes + 1);
  int*   curf    = (int*)alloc(n_nodes);
  int*   curb    = (int*)alloc(n_nodes);
  int*   adjf    = (int*)alloc(n_edges);
  int*   adjb    = (int*)alloc(n_edges);
  int*   partials = (int*)alloc(2 * nb);
  __hip_bfloat16* A1 = (__hip_bfloat16*)alloc((size_t)Mpad * 384 / 2);
  __hip_bfloat16* A2 = (__hip_bfloat16*)alloc((size_t)Mpad * 768 / 2);
  float* hpre    = alloc((size_t)n_nodes * HID);  // shared by layer 1 & 2
  (void)ws_size; (void)n_in;

  hipMemsetAsync(degf, 0, (size_t)n_nodes * 4, stream);
  hipMemsetAsync(degb, 0, (size_t)n_nodes * 4, stream);
  hipMemsetAsync(sum1, 0, 256 * 4, stream);
  hipMemsetAsync(sumsq1, 0, 256 * 4, stream);
  hipMemsetAsync(sum2, 0, 256 * 4, stream);
  hipMemsetAsync(sumsq2, 0, 256 * 4, stream);
  hipMemsetAsync(out_tmp, 0, 256 * 4, stream);

  detect_kernel<<<1, 256, 0, stream>>>((const unsigned int*)x, (const unsigned int*)ei, flags);
  convert_idx_kernel<<<(n_edges + 255) / 256, 256, 0, stream>>>(ei, flags, srcI, dstI, degf, degb, n_edges);
  convert_x_kernel<<<(n_nodes * IN_DIM + 255) / 256, 256, 0, stream>>>(x, flags, A1, n_nodes);
  prep_params_kernel<<<768, 256, 0, stream>>>(
      d_in[2], d_in[3], d_in[4], d_in[5], d_in[6], d_in[7],
      d_in[8], d_in[9], d_in[10], d_in[11], d_in[12], d_in[13],
      d_in[14], d_in[15], d_in[16], d_in[17],
      flags, Wpk1, b1, Wpk2, b2, gamma1, beta1, gamma2, beta2);

  scan_part_kernel<<<2 * nb, 256, 0, stream>>>(degf, degb, offf, offb, partials, n_nodes, nb);
  scan_partials_kernel<<<1, 256, 0, stream>>>(partials, nb);
  scan_add_kernel<<<2 * nb, 256, 0, stream>>>(offf, offb, curf, curb, partials, n_nodes, nb, n_edges);
  fill_adj_kernel<<<(n_edges + 255) / 256, 256, 0, stream>>>(srcI, dstI, curf, curb, adjf, adjb, n_edges);

  // ---- layer 1 ----
  gather_mean_kernel<IN_DIM><<<(2 * n_nodes + 3) / 4, 256, 0, stream>>>(
      A1, adjf, offf, adjb, offb, n_nodes);
  gemm_mfma_kernel<384><<<Mpad / 64, 256, 0, stream>>>(
      A1, Wpk1, b1, hpre, sum1, sumsq1, n_nodes);
  bn_finalize_kernel<<<1, 256, 0, stream>>>(sum1, sumsq1, musig1, (float)n_nodes);
  bn_apply_bf16_kernel<<<n_nodes, 256, 0, stream>>>(hpre, musig1, gamma1, beta1, A2);

  // ---- layer 2 ----
  gather_mean_kernel<HID><<<(2 * n_nodes + 3) / 4, 256, 0, stream>>>(
      A2, adjf, offf, adjb, offb, n_nodes);
  gemm_mfma_kernel<768><<<Mpad / 64, 256, 0, stream>>>(
      A2, Wpk2, b2, hpre, sum2, sumsq2, n_nodes);
  bn_finalize_kernel<<<1, 256, 0, stream>>>(sum2, sumsq2, musig2, (float)n_nodes);
  bn_apply_max_kernel<<<1024, 256, 0, stream>>>(hpre, musig2, gamma2, beta2, n_nodes, out_tmp);
  write_out_kernel<<<1, 256, 0, stream>>>(out_tmp, flags, d_out, out_size);
}

// Round 6
// 500.788 us; speedup vs baseline: 1.1138x; 1.0341x over previous
//
#include <hip/hip_runtime.h>
#include <hip/hip_bf16.h>

#define IN_DIM 128
#define HID 256
#define BN_EPS 1e-5f

typedef __attribute__((ext_vector_type(8))) short bf16x8;
typedef __attribute__((ext_vector_type(16))) float f32x16;

// ---------- dtype helpers ----------
__device__ __forceinline__ float ld_f(const void* p, size_t i, int bf16) {
  if (bf16) return __bfloat162float(((const __hip_bfloat16*)p)[i]);
  return ((const float*)p)[i];
}
__device__ __forceinline__ float blo(unsigned u) { return __uint_as_float(u << 16); }
__device__ __forceinline__ float bhi(unsigned u) { return __uint_as_float(u & 0xffff0000u); }
__device__ __forceinline__ unsigned short f2bf(float f) {
  __hip_bfloat16 b = __float2bfloat16(f);
  return __builtin_bit_cast(unsigned short, b);
}
__device__ __forceinline__ void load_lds16(const void* g, void* l) {
  // async global->LDS DMA: each lane's 16B lands at (wave-uniform l) + lane*16
  __builtin_amdgcn_global_load_lds((const __attribute__((address_space(1))) void*)g,
                                   (__attribute__((address_space(3))) void*)l, 16, 0, 0);
}

// flags[0] = 1 if float arrays are bf16, 0 if f32
// flags[1] = 1 if edge_index is int32, 0 if int64
__global__ void detect_kernel(const unsigned int* __restrict__ xw,
                              const unsigned int* __restrict__ eiw, int* flags) {
  __shared__ int votes, nz;
  if (threadIdx.x == 0) { votes = 0; nz = 0; }
  __syncthreads();
  int i = threadIdx.x;  // 256 threads
  unsigned int e = (xw[i] >> 7) & 0xFFu;
  int v = (e >= 100u && e <= 140u) ? 1 : 0;
  int z = (eiw[2 * i + 1] != 0u) ? 1 : 0;
  atomicAdd(&votes, v);
  atomicAdd(&nz, z);
  __syncthreads();
  if (threadIdx.x == 0) {
    flags[0] = (votes > 128) ? 1 : 0;
    flags[1] = (nz > 0) ? 1 : 0;
  }
}

// convert indices + degree histogram (degf by dst, degb by src)
__global__ void convert_idx_kernel(const void* __restrict__ ei, const int* __restrict__ flags,
                                   int* __restrict__ src, int* __restrict__ dst,
                                   int* __restrict__ degf, int* __restrict__ degb, int n_edges) {
  int i = blockIdx.x * blockDim.x + threadIdx.x;
  if (i >= n_edges) return;
  int s, d;
  if (flags[1]) {
    s = ((const int*)ei)[i];
    d = ((const int*)ei)[n_edges + i];
  } else {
    s = (int)((const long long*)ei)[i];
    d = (int)((const long long*)ei)[n_edges + i];
  }
  src[i] = s;
  dst[i] = d;
  atomicAdd(&degf[d], 1);
  atomicAdd(&degb[s], 1);
}

// x -> bf16 self-slice of A1 (cols 256..383 of row-stride-384 matrix)
__global__ void convert_x_kernel(const void* __restrict__ x, const int* __restrict__ flags,
                                 __hip_bfloat16* __restrict__ A1, int n_nodes) {
  int bf = flags[0];
  size_t idx = (size_t)blockIdx.x * blockDim.x + threadIdx.x;
  size_t n = (size_t)n_nodes * IN_DIM;
  if (idx >= n) return;
  int row = (int)(idx >> 7), j = (int)(idx & 127);
  float v = ld_f(x, idx, bf);
  A1[(size_t)row * 384 + 256 + j] = __float2bfloat16(v);
}

// Pack weights into MFMA B-fragment order + fold biases.
// Wpk layout: element index ((t*STEPS + s)*64 + l)*8 + j  <->  W[k=s*16+(l>>5)*8+j][col=t*32+(l&31)]
__global__ void prep_params_kernel(
    const void* Wl_f1, const void* bl_f1, const void* Wr_f1,
    const void* Wl_b1, const void* bl_b1, const void* Wr_b1,
    const void* Wl_f2, const void* bl_f2, const void* Wr_f2,
    const void* Wl_b2, const void* bl_b2, const void* Wr_b2,
    const void* g1, const void* be1, const void* g2, const void* be2,
    const int* __restrict__ flags,
    __hip_bfloat16* __restrict__ Wpk1, float* __restrict__ b1,
    __hip_bfloat16* __restrict__ Wpk2, float* __restrict__ b2,
    float* __restrict__ gamma1, float* __restrict__ beta1,
    float* __restrict__ gamma2, float* __restrict__ beta2) {
  int bf = flags[0];
  int idx = blockIdx.x * blockDim.x + threadIdx.x;
  if (idx >= 768 * 256) return;
  {  // layer 2 pack (STEPS=48)
    int j = idx & 7, l = (idx >> 3) & 63, rest = idx >> 9;
    int s = rest % 48, t = rest / 48;
    int k = s * 16 + (l >> 5) * 8 + j, col = t * 32 + (l & 31);
    float v;
    if (k < 256)      v = ld_f(Wl_f2, (size_t)k * 256 + col, bf);
    else if (k < 512) v = ld_f(Wl_b2, (size_t)(k - 256) * 256 + col, bf);
    else              v = ld_f(Wr_f2, (size_t)(k - 512) * 256 + col, bf) +
                          ld_f(Wr_b2, (size_t)(k - 512) * 256 + col, bf);
    Wpk2[idx] = __float2bfloat16(v);
  }
  if (idx < 384 * 256) {  // layer 1 pack (STEPS=24)
    int j = idx & 7, l = (idx >> 3) & 63, rest = idx >> 9;
    int s = rest % 24, t = rest / 24;
    int k = s * 16 + (l >> 5) * 8 + j, col = t * 32 + (l & 31);
    float v;
    if (k < 128)      v = ld_f(Wl_f1, (size_t)k * 256 + col, bf);
    else if (k < 256) v = ld_f(Wl_b1, (size_t)(k - 128) * 256 + col, bf);
    else              v = ld_f(Wr_f1, (size_t)(k - 256) * 256 + col, bf) +
                          ld_f(Wr_b1, (size_t)(k - 256) * 256 + col, bf);
    Wpk1[idx] = __float2bfloat16(v);
  }
  if (idx < 256) {
    b1[idx] = ld_f(bl_f1, idx, bf) + ld_f(bl_b1, idx, bf);
    b2[idx] = ld_f(bl_f2, idx, bf) + ld_f(bl_b2, idx, bf);
    gamma1[idx] = ld_f(g1, idx, bf);
    beta1[idx]  = ld_f(be1, idx, bf);
    gamma2[idx] = ld_f(g2, idx, bf);
    beta2[idx]  = ld_f(be2, idx, bf);
  }
}

// ---------- CSR build ----------
__global__ void scan_part_kernel(const int* __restrict__ degf, const int* __restrict__ degb,
                                 int* __restrict__ offf, int* __restrict__ offb,
                                 int* __restrict__ partials, int n, int nb) {
  __shared__ int buf[256];
  const int b = blockIdx.x;
  const int* deg = (b < nb) ? degf : degb;
  int* off = (b < nb) ? offf : offb;
  const int chunk = (b < nb) ? b : (b - nb);
  const int i = chunk * 256 + threadIdx.x;
  int v = (i < n) ? deg[i] : 0;
  buf[threadIdx.x] = v;
  __syncthreads();
  for (int s = 1; s < 256; s <<= 1) {
    int t = (threadIdx.x >= s) ? buf[threadIdx.x - s] : 0;
    __syncthreads();
    buf[threadIdx.x] += t;
    __syncthreads();
  }
  if (i < n) off[i] = buf[threadIdx.x] - v;
  if (threadIdx.x == 255) partials[b] = buf[255];
}

__global__ void scan_partials_kernel(int* __restrict__ partials, int nb) {
  __shared__ int buf[256];
  for (int a = 0; a < 2; ++a) {
    int v = (threadIdx.x < nb) ? partials[a * nb + threadIdx.x] : 0;
    buf[threadIdx.x] = v;
    __syncthreads();
    for (int s = 1; s < 256; s <<= 1) {
      int t = (threadIdx.x >= s) ? buf[threadIdx.x - s] : 0;
      __syncthreads();
      buf[threadIdx.x] += t;
      __syncthreads();
    }
    if (threadIdx.x < nb) partials[a * nb + threadIdx.x] = buf[threadIdx.x] - v;
    __syncthreads();
  }
}

__global__ void scan_add_kernel(int* __restrict__ offf, int* __restrict__ offb,
                                int* __restrict__ curf, int* __restrict__ curb,
                                const int* __restrict__ partials, int n, int nb, int n_edges) {
  const int b = blockIdx.x;
  int* off = (b < nb) ? offf : offb;
  int* cur = (b < nb) ? curf : curb;
  const int chunk = (b < nb) ? b : (b - nb);
  const int i = chunk * 256 + threadIdx.x;
  if (i < n) {
    int v = off[i] + partials[b];
    off[i] = v;
    cur[i] = v;
  }
  if (b == 0 && threadIdx.x == 0) { offf[n] = n_edges; offb[n] = n_edges; }
}

__global__ void fill_adj_kernel(const int* __restrict__ src, const int* __restrict__ dst,
                                int* __restrict__ curf, int* __restrict__ curb,
                                int* __restrict__ adjf, int* __restrict__ adjb, int n_edges) {
  int i = blockIdx.x * blockDim.x + threadIdx.x;
  if (i >= n_edges) return;
  int s = src[i], d = dst[i];
  adjf[atomicAdd(&curf[d], 1)] = s;
  adjb[atomicAdd(&curb[s], 1)] = d;
}

// ---------- gather-mean: depth-2 pipelined row loads, branchless clamped idx ----------
template <int D>
__global__ __launch_bounds__(256) void gather_mean_kernel(
    __hip_bfloat16* __restrict__ A,
    const int* __restrict__ adjf, const int* __restrict__ offf,
    const int* __restrict__ adjb, const int* __restrict__ offb, int n_nodes) {
  constexpr int LPN = D / 8;     // lanes per neighbor row (16B = 8 bf16 each)
  constexpr int NPI = 64 / LPN;  // neighbors per iteration
  const int gw = (int)(((size_t)blockIdx.x * 256 + threadIdx.x) >> 6);
  const int lane = threadIdx.x & 63;
  if (gw >= 2 * n_nodes) return;
  int node, dir;
  const int *adj, *off;
  if (gw < n_nodes) { node = gw;           adj = adjf; off = offf; dir = 0; }
  else              { node = gw - n_nodes; adj = adjb; off = offb; dir = 1; }
  const int s = off[node], e = off[node + 1];
  const int sub = lane / LPN, cl = lane % LPN;
  const size_t coloff = 2 * (size_t)D + cl * 8;  // self-slice column offset
  auto clampi = [&](int i) { return max(min(i, e - 1), 0); };
  float acc[8] = {0.f, 0.f, 0.f, 0.f, 0.f, 0.f, 0.f, 0.f};
  int i = s + sub;
  int a0 = adj[clampi(i)];
  int a1 = adj[clampi(i + NPI)];
  uint4 r0 = *(const uint4*)(A + (size_t)a0 * (3 * D) + coloff);
  for (; i < e; i += NPI) {
    const uint4 r1 = *(const uint4*)(A + (size_t)a1 * (3 * D) + coloff);  // next row, in flight
    const int a2 = adj[clampi(i + 2 * NPI)];
    acc[0] += blo(r0.x); acc[1] += bhi(r0.x);
    acc[2] += blo(r0.y); acc[3] += bhi(r0.y);
    acc[4] += blo(r0.z); acc[5] += bhi(r0.z);
    acc[6] += blo(r0.w); acc[7] += bhi(r0.w);
    r0 = r1; a1 = a2;
  }
#pragma unroll
  for (int o = 32; o >= LPN; o >>= 1) {
#pragma unroll
    for (int k = 0; k < 8; ++k) acc[k] += __shfl_xor(acc[k], o, 64);
  }
  if (sub == 0) {
    const float inv = 1.0f / (float)max(e - s, 1);
    union { unsigned short us[8]; uint4 v; } o;
#pragma unroll
    for (int k = 0; k < 8; ++k) o.us[k] = f2bf(acc[k] * inv);
    *(uint4*)(A + (size_t)node * (3 * D) + dir * D + cl * 8) = o.v;
  }
}

// ---------- MFMA GEMM v4: block = 32 rows x 256 cols, A staged via async DMA to LDS ----------
// 4 waves, each 32r x 64c (2 C-frags, 32 AGPRs). A tile (32 x 64 cols bf16 = 4KB) double-
// buffered in LDS, filled by global_load_lds (16B/lane, 1 inst/wave/k-block), prefetched one
// k-block ahead. LDS layout: chunk (kc,r) at byte (kc*32+r)*16, kc=8-col group, r=row.
// Wave w stages LDS bytes [w*1024,(w+1)*1024): lane i -> kc=w*2+(i>>5), r=i&31.
template <int K>
__global__ __launch_bounds__(256) void gemm_mfma_kernel(
    const __hip_bfloat16* __restrict__ A, const __hip_bfloat16* __restrict__ Wpk,
    const float* __restrict__ bias, float* __restrict__ C,
    float* __restrict__ bnsum, float* __restrict__ bnsum2, int M) {
  constexpr int S = K / 16;    // MFMA k-steps
  constexpr int NKB = K / 64;  // 64-col k-blocks
  __shared__ __align__(16) char Atile[2][4096];
  __shared__ float colsum[256], colsum2[256];
  colsum[threadIdx.x] = 0.f;
  colsum2[threadIdx.x] = 0.f;
  const int wave = threadIdx.x >> 6, lane = threadIdx.x & 63;
  const int rbase = blockIdx.x * 32;
  const int tg0 = wave * 2;  // wave covers col groups tg0, tg0+1

  // per-lane global source for staging; advances 128 bytes per k-block
  const char* gsrc = (const char*)A + (size_t)(rbase + (lane & 31)) * (K * 2)
                   + ((wave * 2 + (lane >> 5)) * 16);
  char* ldst[2] = { &Atile[0][wave * 1024], &Atile[1][wave * 1024] };  // wave-uniform

  load_lds16(gsrc, ldst[0]);  // stage k-block 0

  const __hip_bfloat16* wbase = Wpk + ((size_t)tg0 * S * 64 + lane) * 8;
  bf16x8 w0n = *(const bf16x8*)(wbase);
  bf16x8 w1n = *(const bf16x8*)(wbase + (size_t)S * 512);
  f32x16 acc0 = {}, acc1 = {};
  __syncthreads();  // drains DMA (vmcnt) + colsum init

  for (int kb = 0; kb < NKB; ++kb) {
    if (kb + 1 < NKB)  // prefetch next k-block into other buffer
      load_lds16(gsrc + (size_t)(kb + 1) * 128, ldst[(kb + 1) & 1]);
    const char* abuf = Atile[kb & 1];
#pragma unroll
    for (int st = 0; st < 4; ++st) {
      const int s = kb * 4 + st;
      const bf16x8 a = *(const bf16x8*)(abuf + st * 1024 + (lane >> 5) * 512 + (lane & 31) * 16);
      const bf16x8 w0c = w0n, w1c = w1n;
      const int sn = (s + 1 < S) ? (s + 1) : (S - 1);  // clamped W prefetch
      w0n = *(const bf16x8*)(wbase + (size_t)sn * 512);
      w1n = *(const bf16x8*)(wbase + (size_t)S * 512 + (size_t)sn * 512);
      acc0 = __builtin_amdgcn_mfma_f32_32x32x16_bf16(a, w0c, acc0, 0, 0, 0);
      acc1 = __builtin_amdgcn_mfma_f32_32x32x16_bf16(a, w1c, acc1, 0, 0, 0);
    }
    __syncthreads();  // all waves done reading buf[kb&1]; DMA for kb+1 drained here
  }

  f32x16 accs[2] = {acc0, acc1};
#pragma unroll
  for (int t = 0; t < 2; ++t) {
    const int col = (tg0 + t) * 32 + (lane & 31);
    const float bj = bias[col];
    float ls = 0.f, ls2 = 0.f;
#pragma unroll
    for (int r = 0; r < 16; ++r) {
      const int row = rbase + (r & 3) + 8 * (r >> 2) + 4 * (lane >> 5);
      if (row < M) {
        float v = accs[t][r] + bj;
        C[(size_t)row * 256 + col] = v;
        ls += v;
        ls2 = fmaf(v, v, ls2);
      }
    }
    atomicAdd(&colsum[col], ls);
    atomicAdd(&colsum2[col], ls2);
  }
  __syncthreads();
  atomicAdd(&bnsum[threadIdx.x], colsum[threadIdx.x]);
  atomicAdd(&bnsum2[threadIdx.x], colsum2[threadIdx.x]);
}

// ---------- BN apply (finalize fused: each block recomputes mu/rsqrt from sums) ----------
// BN+ReLU h1 -> bf16 self-slice of A2 (cols 512..767, row stride 768)
__global__ void bn_apply_bf16_kernel(const float* __restrict__ hpre,
                                     const float* __restrict__ sum, const float* __restrict__ sumsq,
                                     const float* __restrict__ gamma, const float* __restrict__ beta,
                                     __hip_bfloat16* __restrict__ A2, int n_nodes, float inv_n) {
  int j = threadIdx.x;
  float mu = sum[j] * inv_n;
  float rs = rsqrtf(fmaxf(sumsq[j] * inv_n - mu * mu, 0.f) + BN_EPS);
  float g = gamma[j] * rs, b = fmaf(-mu, g, beta[j]);  // v*g + b
  for (int row = blockIdx.x; row < n_nodes; row += gridDim.x) {
    float v = hpre[(size_t)row * 256 + j];
    v = fmaxf(fmaf(v, g, b), 0.f);
    A2[(size_t)row * 768 + 512 + j] = __float2bfloat16(v);
  }
}

__global__ void bn_apply_max_kernel(const float* __restrict__ h,
                                    const float* __restrict__ sum, const float* __restrict__ sumsq,
                                    const float* __restrict__ gamma, const float* __restrict__ beta,
                                    int n_nodes, float inv_n, float* __restrict__ out_tmp) {
  int j = threadIdx.x;
  float mu = sum[j] * inv_n;
  float rs = rsqrtf(fmaxf(sumsq[j] * inv_n - mu * mu, 0.f) + BN_EPS);
  float g = gamma[j] * rs, b = fmaf(-mu, g, beta[j]);
  float m = 0.f;  // ReLU output >= 0
  for (int n = blockIdx.x; n < n_nodes; n += gridDim.x) {
    float v = h[(size_t)n * HID + j];
    v = fmaxf(fmaf(v, g, b), 0.f);
    m = fmaxf(m, v);
  }
  atomicMax((int*)&out_tmp[j], __float_as_int(m));
}

__global__ void write_out_kernel(const float* __restrict__ out_tmp, const int* __restrict__ flags,
                                 void* __restrict__ out, int out_size) {
  int j = threadIdx.x;
  if (j >= out_size) return;
  float v = out_tmp[j];
  if (flags[0]) ((__hip_bfloat16*)out)[j] = __float2bfloat16(v);
  else          ((float*)out)[j] = v;
}

extern "C" void kernel_launch(void* const* d_in, const int* in_sizes, int n_in,
                              void* d_out, int out_size, void* d_ws, size_t ws_size,
                              hipStream_t stream) {
  const void* x  = d_in[0];
  const void* ei = d_in[1];
  const int n_nodes = in_sizes[0] / IN_DIM;
  const int n_edges = in_sizes[1] / 2;
  const int nb = (n_nodes + 255) / 256;
  const int Mpad = (n_nodes + 63) & ~63;

  float* ws = (float*)d_ws;
  size_t off = 0;
  auto alloc = [&](size_t n) {
    float* p = ws + off;
    off += (n + 1023) & ~(size_t)1023;
    return p;
  };
  int*   flags   = (int*)alloc(1024);
  __hip_bfloat16* Wpk1 = (__hip_bfloat16*)alloc(384 * 256 / 2);
  __hip_bfloat16* Wpk2 = (__hip_bfloat16*)alloc(768 * 256 / 2);
  float* b1      = alloc(256);
  float* b2      = alloc(256);
  float* gamma1  = alloc(256);
  float* beta1   = alloc(256);
  float* gamma2  = alloc(256);
  float* beta2   = alloc(256);
  // contiguous zero region: degf | degb | sum1 sumsq1 sum2 sumsq2 out_tmp
  float* zeros   = alloc(2 * (size_t)n_nodes + 1280);
  int*   degf    = (int*)zeros;
  int*   degb    = degf + n_nodes;
  float* sum1    = zeros + 2 * (size_t)n_nodes;
  float* sumsq1  = sum1 + 256;
  float* sum2    = sum1 + 512;
  float* sumsq2  = sum1 + 768;
  float* out_tmp = sum1 + 1024;
  int*   srcI    = (int*)alloc(n_edges);
  int*   dstI    = (int*)alloc(n_edges);
  int*   offf    = (int*)alloc(n_nodes + 1);
  int*   offb    = (int*)alloc(n_nodes + 1);
  int*   curf    = (int*)alloc(n_nodes);
  int*   curb    = (int*)alloc(n_nodes);
  int*   adjf    = (int*)alloc(n_edges);
  int*   adjb    = (int*)alloc(n_edges);
  int*   partials = (int*)alloc(2 * nb);
  __hip_bfloat16* A1 = (__hip_bfloat16*)alloc((size_t)Mpad * 384 / 2);
  __hip_bfloat16* A2 = (__hip_bfloat16*)alloc((size_t)Mpad * 768 / 2);
  float* hpre    = alloc((size_t)n_nodes * HID);  // shared by layer 1 & 2
  (void)ws_size; (void)n_in;

  hipMemsetAsync(zeros, 0, (2 * (size_t)n_nodes + 1280) * 4, stream);

  detect_kernel<<<1, 256, 0, stream>>>((const unsigned int*)x, (const unsigned int*)ei, flags);
  convert_idx_kernel<<<(n_edges + 255) / 256, 256, 0, stream>>>(ei, flags, srcI, dstI, degf, degb, n_edges);
  convert_x_kernel<<<(n_nodes * IN_DIM + 255) / 256, 256, 0, stream>>>(x, flags, A1, n_nodes);
  prep_params_kernel<<<768, 256, 0, stream>>>(
      d_in[2], d_in[3], d_in[4], d_in[5], d_in[6], d_in[7],
      d_in[8], d_in[9], d_in[10], d_in[11], d_in[12], d_in[13],
      d_in[14], d_in[15], d_in[16], d_in[17],
      flags, Wpk1, b1, Wpk2, b2, gamma1, beta1, gamma2, beta2);

  scan_part_kernel<<<2 * nb, 256, 0, stream>>>(degf, degb, offf, offb, partials, n_nodes, nb);
  scan_partials_kernel<<<1, 256, 0, stream>>>(partials, nb);
  scan_add_kernel<<<2 * nb, 256, 0, stream>>>(offf, offb, curf, curb, partials, n_nodes, nb, n_edges);
  fill_adj_kernel<<<(n_edges + 255) / 256, 256, 0, stream>>>(srcI, dstI, curf, curb, adjf, adjb, n_edges);

  const float inv_n = 1.0f / (float)n_nodes;
  const int gemm_grid = (n_nodes + 31) / 32;

  // ---- layer 1 ----
  gather_mean_kernel<IN_DIM><<<(2 * n_nodes + 3) / 4, 256, 0, stream>>>(
      A1, adjf, offf, adjb, offb, n_nodes);
  gemm_mfma_kernel<384><<<gemm_grid, 256, 0, stream>>>(
      A1, Wpk1, b1, hpre, sum1, sumsq1, n_nodes);
  bn_apply_bf16_kernel<<<1024, 256, 0, stream>>>(hpre, sum1, sumsq1, gamma1, beta1, A2, n_nodes, inv_n);

  // ---- layer 2 ----
  gather_mean_kernel<HID><<<(2 * n_nodes + 3) / 4, 256, 0, stream>>>(
      A2, adjf, offf, adjb, offb, n_nodes);
  gemm_mfma_kernel<768><<<gemm_grid, 256, 0, stream>>>(
      A2, Wpk2, b2, hpre, sum2, sumsq2, n_nodes);
  bn_apply_max_kernel<<<1024, 256, 0, stream>>>(hpre, sum2, sumsq2, gamma2, beta2, n_nodes, inv_n, out_tmp);
  write_out_kernel<<<1, 256, 0, stream>>>(out_tmp, flags, d_out, out_size);
}

// Round 7
// 446.372 us; speedup vs baseline: 1.2495x; 1.1219x over previous
//
#include <hip/hip_runtime.h>
#include <hip/hip_bf16.h>

#define IN_DIM 128
#define HID 256
#define BN_EPS 1e-5f

typedef __attribute__((ext_vector_type(8))) short bf16x8;
typedef __attribute__((ext_vector_type(16))) float f32x16;

// ---------- helpers ----------
__device__ __forceinline__ float ld_f(const void* p, size_t i, int bf16) {
  if (bf16) return __bfloat162float(((const __hip_bfloat16*)p)[i]);
  return ((const float*)p)[i];
}
__device__ __forceinline__ float blo(unsigned u) { return __uint_as_float(u << 16); }
__device__ __forceinline__ float bhi(unsigned u) { return __uint_as_float(u & 0xffff0000u); }
__device__ __forceinline__ unsigned short f2bf(float f) {
  __hip_bfloat16 b = __float2bfloat16(f);
  return __builtin_bit_cast(unsigned short, b);
}
__device__ __forceinline__ void load_lds16(const void* g, void* l) {
  __builtin_amdgcn_global_load_lds((const __attribute__((address_space(1))) void*)g,
                                   (__attribute__((address_space(3))) void*)l, 16, 0, 0);
}
// order-preserving float->uint key (monotone increasing); init 0 is -NaN (neutral for max)
__device__ __forceinline__ unsigned fkey(float v) {
  unsigned s = __float_as_uint(v);
  return (s & 0x80000000u) ? ~s : (s | 0x80000000u);
}
__device__ __forceinline__ float finv(unsigned k) {
  unsigned s = (k & 0x80000000u) ? (k ^ 0x80000000u) : ~k;
  return __uint_as_float(s);
}

// ---------- mega prep: flag detect (per block) + idx/histogram + x->A1 + W packs ----------
__global__ void prep_kernel(
    const void* __restrict__ x, const void* __restrict__ ei,
    const void* Wl_f1, const void* bl_f1, const void* Wr_f1,
    const void* Wl_b1, const void* bl_b1, const void* Wr_b1,
    const void* Wl_f2, const void* bl_f2, const void* Wr_f2,
    const void* Wl_b2, const void* bl_b2, const void* Wr_b2,
    const void* g1, const void* be1, const void* g2, const void* be2,
    int* __restrict__ src, int* __restrict__ dst,
    int* __restrict__ degf, int* __restrict__ degb,
    __hip_bfloat16* __restrict__ A1,
    __hip_bfloat16* __restrict__ Wpk1, float* __restrict__ b1,
    __hip_bfloat16* __restrict__ Wpk2, float* __restrict__ b2,
    float* __restrict__ gamma1, float* __restrict__ beta1,
    float* __restrict__ gamma2, float* __restrict__ beta2,
    int n_nodes, int n_edges) {
  __shared__ int votes, nz;
  if (threadIdx.x == 0) { votes = 0; nz = 0; }
  __syncthreads();
  {
    unsigned e = (((const unsigned*)x)[threadIdx.x] >> 7) & 0xFFu;
    if (e >= 100u && e <= 140u) atomicAdd(&votes, 1);
    if (((const unsigned*)ei)[2 * threadIdx.x + 1] != 0u) atomicAdd(&nz, 1);
  }
  __syncthreads();
  const int bf = (votes > 128) ? 1 : 0;
  const int i32 = (nz > 0) ? 1 : 0;
  const int tid = blockIdx.x * 256 + threadIdx.x;
  const int nt = gridDim.x * 256;
  // edges + degree histogram
  for (int i = tid; i < n_edges; i += nt) {
    int s, d;
    if (i32) { s = ((const int*)ei)[i]; d = ((const int*)ei)[n_edges + i]; }
    else     { s = (int)((const long long*)ei)[i]; d = (int)((const long long*)ei)[n_edges + i]; }
    src[i] = s; dst[i] = d;
    atomicAdd(&degf[d], 1);
    atomicAdd(&degb[s], 1);
  }
  // x -> bf16 self-slice of A1 (cols 256..383, row stride 384)
  for (size_t idx = tid; idx < (size_t)n_nodes * IN_DIM; idx += nt) {
    int row = (int)(idx >> 7), j = (int)(idx & 127);
    A1[(size_t)row * 384 + 256 + j] = __float2bfloat16(ld_f(x, idx, bf));
  }
  // W packs (MFMA B-frag order) + biases/BN params
  for (int idx = tid; idx < 768 * 256; idx += nt) {
    {
      int j = idx & 7, l = (idx >> 3) & 63, rest = idx >> 9;
      int s = rest % 48, t = rest / 48;
      int k = s * 16 + (l >> 5) * 8 + j, col = t * 32 + (l & 31);
      float v;
      if (k < 256)      v = ld_f(Wl_f2, (size_t)k * 256 + col, bf);
      else if (k < 512) v = ld_f(Wl_b2, (size_t)(k - 256) * 256 + col, bf);
      else              v = ld_f(Wr_f2, (size_t)(k - 512) * 256 + col, bf) +
                            ld_f(Wr_b2, (size_t)(k - 512) * 256 + col, bf);
      Wpk2[idx] = __float2bfloat16(v);
    }
    if (idx < 384 * 256) {
      int j = idx & 7, l = (idx >> 3) & 63, rest = idx >> 9;
      int s = rest % 24, t = rest / 24;
      int k = s * 16 + (l >> 5) * 8 + j, col = t * 32 + (l & 31);
      float v;
      if (k < 128)      v = ld_f(Wl_f1, (size_t)k * 256 + col, bf);
      else if (k < 256) v = ld_f(Wl_b1, (size_t)(k - 128) * 256 + col, bf);
      else              v = ld_f(Wr_f1, (size_t)(k - 256) * 256 + col, bf) +
                            ld_f(Wr_b1, (size_t)(k - 256) * 256 + col, bf);
      Wpk1[idx] = __float2bfloat16(v);
    }
    if (idx < 256) {
      b1[idx] = ld_f(bl_f1, idx, bf) + ld_f(bl_b1, idx, bf);
      b2[idx] = ld_f(bl_f2, idx, bf) + ld_f(bl_b2, idx, bf);
      gamma1[idx] = ld_f(g1, idx, bf);
      beta1[idx]  = ld_f(be1, idx, bf);
      gamma2[idx] = ld_f(g2, idx, bf);
      beta2[idx]  = ld_f(be2, idx, bf);
    }
  }
}

// ---------- CSR build ----------
__global__ void scan_part_kernel(const int* __restrict__ degf, const int* __restrict__ degb,
                                 int* __restrict__ offf, int* __restrict__ offb,
                                 int* __restrict__ partials, int n, int nb) {
  __shared__ int buf[256];
  const int b = blockIdx.x;
  const int* deg = (b < nb) ? degf : degb;
  int* off = (b < nb) ? offf : offb;
  const int chunk = (b < nb) ? b : (b - nb);
  const int i = chunk * 256 + threadIdx.x;
  int v = (i < n) ? deg[i] : 0;
  buf[threadIdx.x] = v;
  __syncthreads();
  for (int s = 1; s < 256; s <<= 1) {
    int t = (threadIdx.x >= s) ? buf[threadIdx.x - s] : 0;
    __syncthreads();
    buf[threadIdx.x] += t;
    __syncthreads();
  }
  if (i < n) off[i] = buf[threadIdx.x] - v;
  if (threadIdx.x == 255) partials[b] = buf[255];
}

__global__ void scan_partials_kernel(int* __restrict__ partials, int nb) {
  __shared__ int buf[256];
  for (int a = 0; a < 2; ++a) {
    int v = (threadIdx.x < nb) ? partials[a * nb + threadIdx.x] : 0;
    buf[threadIdx.x] = v;
    __syncthreads();
    for (int s = 1; s < 256; s <<= 1) {
      int t = (threadIdx.x >= s) ? buf[threadIdx.x - s] : 0;
      __syncthreads();
      buf[threadIdx.x] += t;
      __syncthreads();
    }
    if (threadIdx.x < nb) partials[a * nb + threadIdx.x] = buf[threadIdx.x] - v;
    __syncthreads();
  }
}

__global__ void scan_add_kernel(int* __restrict__ offf, int* __restrict__ offb,
                                int* __restrict__ curf, int* __restrict__ curb,
                                const int* __restrict__ partials, int n, int nb, int n_edges) {
  const int b = blockIdx.x;
  int* off = (b < nb) ? offf : offb;
  int* cur = (b < nb) ? curf : curb;
  const int chunk = (b < nb) ? b : (b - nb);
  const int i = chunk * 256 + threadIdx.x;
  if (i < n) {
    int v = off[i] + partials[b];
    off[i] = v;
    cur[i] = v;
  }
  if (b == 0 && threadIdx.x == 0) { offf[n] = n_edges; offb[n] = n_edges; }
}

__global__ void fill_adj_kernel(const int* __restrict__ src, const int* __restrict__ dst,
                                int* __restrict__ curf, int* __restrict__ curb,
                                int* __restrict__ adjf, int* __restrict__ adjb, int n_edges) {
  int i = blockIdx.x * blockDim.x + threadIdx.x;
  if (i >= n_edges) return;
  int s = src[i], d = dst[i];
  adjf[atomicAdd(&curf[d], 1)] = s;
  adjb[atomicAdd(&curb[s], 1)] = d;
}

// ---------- gather-mean: depth-2 pipelined row loads, branchless clamped idx ----------
template <int D>
__global__ __launch_bounds__(256) void gather_mean_kernel(
    __hip_bfloat16* __restrict__ A,
    const int* __restrict__ adjf, const int* __restrict__ offf,
    const int* __restrict__ adjb, const int* __restrict__ offb, int n_nodes) {
  constexpr int LPN = D / 8;
  constexpr int NPI = 64 / LPN;
  const int gw = (int)(((size_t)blockIdx.x * 256 + threadIdx.x) >> 6);
  const int lane = threadIdx.x & 63;
  if (gw >= 2 * n_nodes) return;
  int node, dir;
  const int *adj, *off;
  if (gw < n_nodes) { node = gw;           adj = adjf; off = offf; dir = 0; }
  else              { node = gw - n_nodes; adj = adjb; off = offb; dir = 1; }
  const int s = off[node], e = off[node + 1];
  const int sub = lane / LPN, cl = lane % LPN;
  const size_t coloff = 2 * (size_t)D + cl * 8;
  auto clampi = [&](int i) { return max(min(i, e - 1), 0); };
  float acc[8] = {0.f, 0.f, 0.f, 0.f, 0.f, 0.f, 0.f, 0.f};
  int i = s + sub;
  int a0 = adj[clampi(i)];
  int a1 = adj[clampi(i + NPI)];
  uint4 r0 = *(const uint4*)(A + (size_t)a0 * (3 * D) + coloff);
  for (; i < e; i += NPI) {
    const uint4 r1 = *(const uint4*)(A + (size_t)a1 * (3 * D) + coloff);
    const int a2 = adj[clampi(i + 2 * NPI)];
    acc[0] += blo(r0.x); acc[1] += bhi(r0.x);
    acc[2] += blo(r0.y); acc[3] += bhi(r0.y);
    acc[4] += blo(r0.z); acc[5] += bhi(r0.z);
    acc[6] += blo(r0.w); acc[7] += bhi(r0.w);
    r0 = r1; a1 = a2;
  }
#pragma unroll
  for (int o = 32; o >= LPN; o >>= 1) {
#pragma unroll
    for (int k = 0; k < 8; ++k) acc[k] += __shfl_xor(acc[k], o, 64);
  }
  if (sub == 0) {
    const float inv = 1.0f / (float)max(e - s, 1);
    union { unsigned short us[8]; uint4 v; } o;
#pragma unroll
    for (int k = 0; k < 8; ++k) o.us[k] = f2bf(acc[k] * inv);
    *(uint4*)(A + (size_t)node * (3 * D) + dir * D + cl * 8) = o.v;
  }
}

// ---------- MFMA GEMM v5: single-barrier full-K LDS A-staging ----------
// block = 32 rows x 256 cols, 4 waves x 64 cols (2 C-frags / 32 AGPRs).
// Whole A tile (32 x K bf16) staged by NKB async DMAs per wave, ONE __syncthreads,
// then a barrier-free K-loop (W depth-3 register prefetch, A depth-2 LDS prefetch).
// Epilogue fuses BN sum/sumsq and order-key column max/min.
// STORE: write bf16 pre-BN values to Cb (row stride 768, col offset 512) [layer 1].
template <int K, bool STORE>
__global__ __launch_bounds__(256) void gemm_mfma_kernel(
    const __hip_bfloat16* __restrict__ A, const __hip_bfloat16* __restrict__ Wpk,
    const float* __restrict__ bias, __hip_bfloat16* __restrict__ Cb,
    float* __restrict__ bnsum, float* __restrict__ bnsum2,
    unsigned* __restrict__ gmax, unsigned* __restrict__ gmin, int M) {
  constexpr int S = K / 16;    // MFMA k-steps
  constexpr int NKB = K / 64;  // 4KB staging chunks
  __shared__ __align__(16) char Atile[NKB][4096];
  __shared__ float colsum[256], colsum2[256];
  __shared__ unsigned cmax[256], cmin[256];
  colsum[threadIdx.x] = 0.f; colsum2[threadIdx.x] = 0.f;
  cmax[threadIdx.x] = 0u; cmin[threadIdx.x] = 0u;
  const int wave = threadIdx.x >> 6, lane = threadIdx.x & 63;
  const int rbase = blockIdx.x * 32;
  const int tg0 = wave * 2;
  const char* gsrc = (const char*)A + (size_t)(rbase + (lane & 31)) * (K * 2)
                   + ((wave * 2 + (lane >> 5)) * 16);
  char* ldst = &Atile[0][wave * 1024];
#pragma unroll
  for (int kb = 0; kb < NKB; ++kb)  // all DMAs in flight at once
    load_lds16(gsrc + (size_t)kb * 128, ldst + kb * 4096);

  const __hip_bfloat16* wbase = Wpk + ((size_t)tg0 * S * 64 + lane) * 8;
  bf16x8 w0b[3], w1b[3];
#pragma unroll
  for (int d = 0; d < 3; ++d) {
    w0b[d] = *(const bf16x8*)(wbase + (size_t)d * 512);
    w1b[d] = *(const bf16x8*)(wbase + (size_t)S * 512 + (size_t)d * 512);
  }
  f32x16 acc0 = {}, acc1 = {};
  __syncthreads();  // single barrier: drains all staging DMAs (vmcnt 0)

  const char* abase = &Atile[0][0];
  const int aoff = (lane >> 5) * 512 + (lane & 31) * 16;
  bf16x8 a0 = *(const bf16x8*)(abase + aoff);
  bf16x8 a1v = *(const bf16x8*)(abase + 1024 + aoff);
#pragma unroll
  for (int s = 0; s < S; ++s) {
    const int slot = s % 3;
    const bf16x8 a = a0, w0 = w0b[slot], w1 = w1b[slot];
    a0 = a1v;
    const int sa = (s + 2 < S) ? s + 2 : S - 1;
    a1v = *(const bf16x8*)(abase + (size_t)sa * 1024 + aoff);
    const int sn = (s + 3 < S) ? s + 3 : S - 1;
    w0b[slot] = *(const bf16x8*)(wbase + (size_t)sn * 512);
    w1b[slot] = *(const bf16x8*)(wbase + (size_t)S * 512 + (size_t)sn * 512);
    acc0 = __builtin_amdgcn_mfma_f32_32x32x16_bf16(a, w0, acc0, 0, 0, 0);
    acc1 = __builtin_amdgcn_mfma_f32_32x32x16_bf16(a, w1, acc1, 0, 0, 0);
  }

  f32x16 accs[2] = {acc0, acc1};
#pragma unroll
  for (int t = 0; t < 2; ++t) {
    const int col = (tg0 + t) * 32 + (lane & 31);
    const float bj = bias[col];
    float ls = 0.f, ls2 = 0.f, lmax = -INFINITY, lmin = INFINITY;
#pragma unroll
    for (int r = 0; r < 16; ++r) {
      const int row = rbase + (r & 3) + 8 * (r >> 2) + 4 * (lane >> 5);
      if (row < M) {
        float v = accs[t][r] + bj;
        if (STORE) Cb[(size_t)row * 768 + 512 + col] = __float2bfloat16(v);
        ls += v;
        ls2 = fmaf(v, v, ls2);
        lmax = fmaxf(lmax, v);
        lmin = fminf(lmin, v);
      }
    }
    atomicAdd(&colsum[col], ls);
    atomicAdd(&colsum2[col], ls2);
    atomicMax(&cmax[col], fkey(lmax));
    atomicMax(&cmin[col], ~fkey(lmin));
  }
  __syncthreads();
  atomicAdd(&bnsum[threadIdx.x], colsum[threadIdx.x]);
  atomicAdd(&bnsum2[threadIdx.x], colsum2[threadIdx.x]);
  atomicMax(&gmax[threadIdx.x], cmax[threadIdx.x]);
  atomicMax(&gmin[threadIdx.x], cmin[threadIdx.x]);
}

// ---------- BN+ReLU in place on A2 self-slice (bf16 -> bf16) ----------
__global__ void bn_apply_kernel(__hip_bfloat16* __restrict__ A2,
                                const float* __restrict__ sum, const float* __restrict__ sumsq,
                                const float* __restrict__ gamma, const float* __restrict__ beta,
                                int n_nodes, float inv_n) {
  int j = threadIdx.x;
  float mu = sum[j] * inv_n;
  float rs = rsqrtf(fmaxf(sumsq[j] * inv_n - mu * mu, 0.f) + BN_EPS);
  float g = gamma[j] * rs, b = fmaf(-mu, g, beta[j]);
  for (int row = blockIdx.x; row < n_nodes; row += gridDim.x) {
    size_t idx = (size_t)row * 768 + 512 + j;
    float v = __bfloat162float(A2[idx]);
    v = fmaxf(fmaf(v, g, b), 0.f);
    A2[idx] = __float2bfloat16(v);
  }
}

// ---------- finalize: out[j] from fused layer-2 stats (monotone max/min trick) ----------
__global__ void finalize_kernel(const unsigned* __restrict__ xw,
                                const float* __restrict__ sum, const float* __restrict__ sumsq,
                                const unsigned* __restrict__ gmax, const unsigned* __restrict__ gmin,
                                const float* __restrict__ gamma, const float* __restrict__ beta,
                                float inv_n, void* __restrict__ out, int out_size) {
  __shared__ int votes;
  if (threadIdx.x == 0) votes = 0;
  __syncthreads();
  unsigned e = (xw[threadIdx.x] >> 7) & 0xFFu;
  if (e >= 100u && e <= 140u) atomicAdd(&votes, 1);
  __syncthreads();
  int bf = votes > 128;
  int j = threadIdx.x;
  if (j >= out_size) return;
  float mu = sum[j] * inv_n;
  float rs = rsqrtf(fmaxf(sumsq[j] * inv_n - mu * mu, 0.f) + BN_EPS);
  float g = gamma[j] * rs, b = fmaf(-mu, g, beta[j]);
  float vmax = finv(gmax[j]);
  float vmin = finv(~gmin[j]);
  float v = fmaxf(fmaf(g, (g >= 0.f) ? vmax : vmin, b), 0.f);
  if (bf) ((__hip_bfloat16*)out)[j] = __float2bfloat16(v);
  else    ((float*)out)[j] = v;
}

extern "C" void kernel_launch(void* const* d_in, const int* in_sizes, int n_in,
                              void* d_out, int out_size, void* d_ws, size_t ws_size,
                              hipStream_t stream) {
  const void* x  = d_in[0];
  const void* ei = d_in[1];
  const int n_nodes = in_sizes[0] / IN_DIM;
  const int n_edges = in_sizes[1] / 2;
  const int nb = (n_nodes + 255) / 256;
  const int Mpad = (n_nodes + 63) & ~63;

  float* ws = (float*)d_ws;
  size_t off = 0;
  auto alloc = [&](size_t n) {
    float* p = ws + off;
    off += (n + 1023) & ~(size_t)1023;
    return p;
  };
  __hip_bfloat16* Wpk1 = (__hip_bfloat16*)alloc(384 * 256 / 2);
  __hip_bfloat16* Wpk2 = (__hip_bfloat16*)alloc(768 * 256 / 2);
  float* b1      = alloc(256);
  float* b2      = alloc(256);
  float* gamma1  = alloc(256);
  float* beta1   = alloc(256);
  float* gamma2  = alloc(256);
  float* beta2   = alloc(256);
  // contiguous zero region: degf | degb | sums/keys
  float* zeros   = alloc(2 * (size_t)n_nodes + 2048);
  int*   degf    = (int*)zeros;
  int*   degb    = degf + n_nodes;
  float* sum1    = zeros + 2 * (size_t)n_nodes;
  float* sumsq1  = sum1 + 256;
  float* sum2    = sum1 + 512;
  float* sumsq2  = sum1 + 768;
  unsigned* max1 = (unsigned*)(sum1 + 1024);
  unsigned* min1 = (unsigned*)(sum1 + 1280);
  unsigned* max2 = (unsigned*)(sum1 + 1536);
  unsigned* min2 = (unsigned*)(sum1 + 1792);
  int*   srcI    = (int*)alloc(n_edges);
  int*   dstI    = (int*)alloc(n_edges);
  int*   offf    = (int*)alloc(n_nodes + 1);
  int*   offb    = (int*)alloc(n_nodes + 1);
  int*   curf    = (int*)alloc(n_nodes);
  int*   curb    = (int*)alloc(n_nodes);
  int*   adjf    = (int*)alloc(n_edges);
  int*   adjb    = (int*)alloc(n_edges);
  int*   partials = (int*)alloc(2 * nb);
  __hip_bfloat16* A1 = (__hip_bfloat16*)alloc((size_t)Mpad * 384 / 2);
  __hip_bfloat16* A2 = (__hip_bfloat16*)alloc((size_t)Mpad * 768 / 2);
  (void)ws_size; (void)n_in;

  hipMemsetAsync(zeros, 0, (2 * (size_t)n_nodes + 2048) * 4, stream);

  const int pgrid = (n_edges + 255) / 256;
  prep_kernel<<<pgrid, 256, 0, stream>>>(
      x, ei,
      d_in[2], d_in[3], d_in[4], d_in[5], d_in[6], d_in[7],
      d_in[8], d_in[9], d_in[10], d_in[11], d_in[12], d_in[13],
      d_in[14], d_in[15], d_in[16], d_in[17],
      srcI, dstI, degf, degb, A1,
      Wpk1, b1, Wpk2, b2, gamma1, beta1, gamma2, beta2, n_nodes, n_edges);

  scan_part_kernel<<<2 * nb, 256, 0, stream>>>(degf, degb, offf, offb, partials, n_nodes, nb);
  scan_partials_kernel<<<1, 256, 0, stream>>>(partials, nb);
  scan_add_kernel<<<2 * nb, 256, 0, stream>>>(offf, offb, curf, curb, partials, n_nodes, nb, n_edges);
  fill_adj_kernel<<<(n_edges + 255) / 256, 256, 0, stream>>>(srcI, dstI, curf, curb, adjf, adjb, n_edges);

  const float inv_n = 1.0f / (float)n_nodes;
  const int gemm_grid = (n_nodes + 31) / 32;

  // ---- layer 1 ----
  gather_mean_kernel<IN_DIM><<<(2 * n_nodes + 3) / 4, 256, 0, stream>>>(
      A1, adjf, offf, adjb, offb, n_nodes);
  gemm_mfma_kernel<384, true><<<gemm_grid, 256, 0, stream>>>(
      A1, Wpk1, b1, A2, sum1, sumsq1, max1, min1, n_nodes);
  bn_apply_kernel<<<1024, 256, 0, stream>>>(A2, sum1, sumsq1, gamma1, beta1, n_nodes, inv_n);

  // ---- layer 2 (no C store; stats + max/min fused) ----
  gather_mean_kernel<HID><<<(2 * n_nodes + 3) / 4, 256, 0, stream>>>(
      A2, adjf, offf, adjb, offb, n_nodes);
  gemm_mfma_kernel<768, false><<<gemm_grid, 256, 0, stream>>>(
      A2, Wpk2, b2, nullptr, sum2, sumsq2, max2, min2, n_nodes);
  finalize_kernel<<<1, 256, 0, stream>>>(
      (const unsigned*)x, sum2, sumsq2, max2, min2, gamma2, beta2, inv_n, d_out, out_size);
}

// Round 8
// 403.305 us; speedup vs baseline: 1.3830x; 1.1068x over previous
//
#include <hip/hip_runtime.h>
#include <hip/hip_bf16.h>

#define IN_DIM 128
#define HID 256
#define BN_EPS 1e-5f

typedef __attribute__((ext_vector_type(8))) short bf16x8;
typedef __attribute__((ext_vector_type(16))) float f32x16;

// ---------- helpers ----------
__device__ __forceinline__ float ld_f(const void* p, size_t i, int bf16) {
  if (bf16) return __bfloat162float(((const __hip_bfloat16*)p)[i]);
  return ((const float*)p)[i];
}
__device__ __forceinline__ float blo(unsigned u) { return __uint_as_float(u << 16); }
__device__ __forceinline__ float bhi(unsigned u) { return __uint_as_float(u & 0xffff0000u); }
__device__ __forceinline__ unsigned short f2bf(float f) {
  __hip_bfloat16 b = __float2bfloat16(f);
  return __builtin_bit_cast(unsigned short, b);
}
__device__ __forceinline__ void load_lds16(const void* g, void* l) {
  __builtin_amdgcn_global_load_lds((const __attribute__((address_space(1))) void*)g,
                                   (__attribute__((address_space(3))) void*)l, 16, 0, 0);
}
// order-preserving float->uint key (monotone increasing); init 0 is neutral for max
__device__ __forceinline__ unsigned fkey(float v) {
  unsigned s = __float_as_uint(v);
  return (s & 0x80000000u) ? ~s : (s | 0x80000000u);
}
__device__ __forceinline__ float finv(unsigned k) {
  unsigned s = (k & 0x80000000u) ? (k ^ 0x80000000u) : ~k;
  return __uint_as_float(s);
}

// ---------- mega prep: flag detect (per block) + idx/histogram + x->A1 + W packs ----------
__global__ void prep_kernel(
    const void* __restrict__ x, const void* __restrict__ ei,
    const void* Wl_f1, const void* bl_f1, const void* Wr_f1,
    const void* Wl_b1, const void* bl_b1, const void* Wr_b1,
    const void* Wl_f2, const void* bl_f2, const void* Wr_f2,
    const void* Wl_b2, const void* bl_b2, const void* Wr_b2,
    const void* g1, const void* be1, const void* g2, const void* be2,
    int* __restrict__ src, int* __restrict__ dst,
    int* __restrict__ degf, int* __restrict__ degb,
    __hip_bfloat16* __restrict__ A1,
    __hip_bfloat16* __restrict__ Wpk1, float* __restrict__ b1,
    __hip_bfloat16* __restrict__ Wpk2, float* __restrict__ b2,
    float* __restrict__ gamma1, float* __restrict__ beta1,
    float* __restrict__ gamma2, float* __restrict__ beta2,
    int n_nodes, int n_edges) {
  __shared__ int votes, nz;
  if (threadIdx.x == 0) { votes = 0; nz = 0; }
  __syncthreads();
  {
    unsigned e = (((const unsigned*)x)[threadIdx.x] >> 7) & 0xFFu;
    if (e >= 100u && e <= 140u) atomicAdd(&votes, 1);
    if (((const unsigned*)ei)[2 * threadIdx.x + 1] != 0u) atomicAdd(&nz, 1);
  }
  __syncthreads();
  const int bf = (votes > 128) ? 1 : 0;
  const int i32 = (nz > 0) ? 1 : 0;
  const int tid = blockIdx.x * 256 + threadIdx.x;
  const int nt = gridDim.x * 256;
  for (int i = tid; i < n_edges; i += nt) {
    int s, d;
    if (i32) { s = ((const int*)ei)[i]; d = ((const int*)ei)[n_edges + i]; }
    else     { s = (int)((const long long*)ei)[i]; d = (int)((const long long*)ei)[n_edges + i]; }
    src[i] = s; dst[i] = d;
    atomicAdd(&degf[d], 1);
    atomicAdd(&degb[s], 1);
  }
  for (size_t idx = tid; idx < (size_t)n_nodes * IN_DIM; idx += nt) {
    int row = (int)(idx >> 7), j = (int)(idx & 127);
    A1[(size_t)row * 384 + 256 + j] = __float2bfloat16(ld_f(x, idx, bf));
  }
  for (int idx = tid; idx < 768 * 256; idx += nt) {
    {
      int j = idx & 7, l = (idx >> 3) & 63, rest = idx >> 9;
      int s = rest % 48, t = rest / 48;
      int k = s * 16 + (l >> 5) * 8 + j, col = t * 32 + (l & 31);
      float v;
      if (k < 256)      v = ld_f(Wl_f2, (size_t)k * 256 + col, bf);
      else if (k < 512) v = ld_f(Wl_b2, (size_t)(k - 256) * 256 + col, bf);
      else              v = ld_f(Wr_f2, (size_t)(k - 512) * 256 + col, bf) +
                            ld_f(Wr_b2, (size_t)(k - 512) * 256 + col, bf);
      Wpk2[idx] = __float2bfloat16(v);
    }
    if (idx < 384 * 256) {
      int j = idx & 7, l = (idx >> 3) & 63, rest = idx >> 9;
      int s = rest % 24, t = rest / 24;
      int k = s * 16 + (l >> 5) * 8 + j, col = t * 32 + (l & 31);
      float v;
      if (k < 128)      v = ld_f(Wl_f1, (size_t)k * 256 + col, bf);
      else if (k < 256) v = ld_f(Wl_b1, (size_t)(k - 128) * 256 + col, bf);
      else              v = ld_f(Wr_f1, (size_t)(k - 256) * 256 + col, bf) +
                            ld_f(Wr_b1, (size_t)(k - 256) * 256 + col, bf);
      Wpk1[idx] = __float2bfloat16(v);
    }
    if (idx < 256) {
      b1[idx] = ld_f(bl_f1, idx, bf) + ld_f(bl_b1, idx, bf);
      b2[idx] = ld_f(bl_f2, idx, bf) + ld_f(bl_b2, idx, bf);
      gamma1[idx] = ld_f(g1, idx, bf);
      beta1[idx]  = ld_f(be1, idx, bf);
      gamma2[idx] = ld_f(g2, idx, bf);
      beta2[idx]  = ld_f(be2, idx, bf);
    }
  }
}

// ---------- CSR build ----------
__global__ void scan_part_kernel(const int* __restrict__ degf, const int* __restrict__ degb,
                                 int* __restrict__ offf, int* __restrict__ offb,
                                 int* __restrict__ partials, int n, int nb) {
  __shared__ int buf[256];
  const int b = blockIdx.x;
  const int* deg = (b < nb) ? degf : degb;
  int* off = (b < nb) ? offf : offb;
  const int chunk = (b < nb) ? b : (b - nb);
  const int i = chunk * 256 + threadIdx.x;
  int v = (i < n) ? deg[i] : 0;
  buf[threadIdx.x] = v;
  __syncthreads();
  for (int s = 1; s < 256; s <<= 1) {
    int t = (threadIdx.x >= s) ? buf[threadIdx.x - s] : 0;
    __syncthreads();
    buf[threadIdx.x] += t;
    __syncthreads();
  }
  if (i < n) off[i] = buf[threadIdx.x] - v;
  if (threadIdx.x == 255) partials[b] = buf[255];
}

__global__ void scan_partials_kernel(int* __restrict__ partials, int nb) {
  __shared__ int buf[256];
  for (int a = 0; a < 2; ++a) {
    int v = (threadIdx.x < nb) ? partials[a * nb + threadIdx.x] : 0;
    buf[threadIdx.x] = v;
    __syncthreads();
    for (int s = 1; s < 256; s <<= 1) {
      int t = (threadIdx.x >= s) ? buf[threadIdx.x - s] : 0;
      __syncthreads();
      buf[threadIdx.x] += t;
      __syncthreads();
    }
    if (threadIdx.x < nb) partials[a * nb + threadIdx.x] = buf[threadIdx.x] - v;
    __syncthreads();
  }
}

__global__ void scan_add_kernel(int* __restrict__ offf, int* __restrict__ offb,
                                int* __restrict__ curf, int* __restrict__ curb,
                                const int* __restrict__ partials, int n, int nb, int n_edges) {
  const int b = blockIdx.x;
  int* off = (b < nb) ? offf : offb;
  int* cur = (b < nb) ? curf : curb;
  const int chunk = (b < nb) ? b : (b - nb);
  const int i = chunk * 256 + threadIdx.x;
  if (i < n) {
    int v = off[i] + partials[b];
    off[i] = v;
    cur[i] = v;
  }
  if (b == 0 && threadIdx.x == 0) { offf[n] = n_edges; offb[n] = n_edges; }
}

__global__ void fill_adj_kernel(const int* __restrict__ src, const int* __restrict__ dst,
                                int* __restrict__ curf, int* __restrict__ curb,
                                int* __restrict__ adjf, int* __restrict__ adjb, int n_edges) {
  int i = blockIdx.x * blockDim.x + threadIdx.x;
  if (i >= n_edges) return;
  int s = src[i], d = dst[i];
  adjf[atomicAdd(&curf[d], 1)] = s;
  adjb[atomicAdd(&curb[s], 1)] = d;
}

// ---------- gather-mean: depth-2 pipelined row loads, branchless clamped idx ----------
template <int D>
__global__ __launch_bounds__(256) void gather_mean_kernel(
    __hip_bfloat16* __restrict__ A,
    const int* __restrict__ adjf, const int* __restrict__ offf,
    const int* __restrict__ adjb, const int* __restrict__ offb, int n_nodes) {
  constexpr int LPN = D / 8;
  constexpr int NPI = 64 / LPN;
  const int gw = (int)(((size_t)blockIdx.x * 256 + threadIdx.x) >> 6);
  const int lane = threadIdx.x & 63;
  if (gw >= 2 * n_nodes) return;
  int node, dir;
  const int *adj, *off;
  if (gw < n_nodes) { node = gw;           adj = adjf; off = offf; dir = 0; }
  else              { node = gw - n_nodes; adj = adjb; off = offb; dir = 1; }
  const int s = off[node], e = off[node + 1];
  const int sub = lane / LPN, cl = lane % LPN;
  const size_t coloff = 2 * (size_t)D + cl * 8;
  auto clampi = [&](int i) { return max(min(i, e - 1), 0); };
  float acc[8] = {0.f, 0.f, 0.f, 0.f, 0.f, 0.f, 0.f, 0.f};
  int i = s + sub;
  int a0 = adj[clampi(i)];
  int a1 = adj[clampi(i + NPI)];
  uint4 r0 = *(const uint4*)(A + (size_t)a0 * (3 * D) + coloff);
  for (; i < e; i += NPI) {
    const uint4 r1 = *(const uint4*)(A + (size_t)a1 * (3 * D) + coloff);
    const int a2 = adj[clampi(i + 2 * NPI)];
    acc[0] += blo(r0.x); acc[1] += bhi(r0.x);
    acc[2] += blo(r0.y); acc[3] += bhi(r0.y);
    acc[4] += blo(r0.z); acc[5] += bhi(r0.z);
    acc[6] += blo(r0.w); acc[7] += bhi(r0.w);
    r0 = r1; a1 = a2;
  }
#pragma unroll
  for (int o = 32; o >= LPN; o >>= 1) {
#pragma unroll
    for (int k = 0; k < 8; ++k) acc[k] += __shfl_xor(acc[k], o, 64);
  }
  if (sub == 0) {
    const float inv = 1.0f / (float)max(e - s, 1);
    union { unsigned short us[8]; uint4 v; } o;
#pragma unroll
    for (int k = 0; k < 8; ++k) o.us[k] = f2bf(acc[k] * inv);
    *(uint4*)(A + (size_t)node * (3 * D) + dir * D + cl * 8) = o.v;
  }
}

// ---------- MFMA GEMM v6: 128 rows x 256 cols / block, BK=128 double-buffered LDS ----------
// 4 waves, each 64r x 128c (8 C-frags / 128 AGPRs). One barrier per K-iter; next chunk's
// 8 DMAs/wave issued right after the barrier so the DMA flight overlaps 64 MFMAs/wave.
// LDS chunk layout: microtile (k-step d 0..7, row-group g 0..3) = 32 rows x 16 cols at
// offset (d*4+g)*1024; within: row r at r*32, k-half h at +h*16 (= DMA lane*16 order).
// Epilogue fuses BN sum/sumsq + order-key column max/min; STORE (layer 1) writes bf16
// pre-BN into A2 self-slice (row stride 768, col offset 512).
template <int K, bool STORE>
__global__ __launch_bounds__(256, 2) void gemm_mfma_kernel(
    const __hip_bfloat16* __restrict__ A, const __hip_bfloat16* __restrict__ Wpk,
    const float* __restrict__ bias, __hip_bfloat16* __restrict__ Cb,
    float* __restrict__ bnsum, float* __restrict__ bnsum2,
    unsigned* __restrict__ gmax, unsigned* __restrict__ gmin, int M) {
  constexpr int S = K / 16;    // total k-steps
  constexpr int NIT = K / 128; // BK=128 iterations
  __shared__ __align__(16) char Atile[2][32768];
  __shared__ float colsum[256], colsum2[256];
  __shared__ unsigned cmax[256], cmin[256];
  colsum[threadIdx.x] = 0.f; colsum2[threadIdx.x] = 0.f;
  cmax[threadIdx.x] = 0u; cmin[threadIdx.x] = 0u;
  const int wave = threadIdx.x >> 6, lane = threadIdx.x & 63;
  const int rw = wave >> 1, cw = wave & 1;  // wave tile: rows rw*64, cols cw*128
  const int rbase = blockIdx.x * 128;
  // staging: wave stages row-group `wave`; lane -> row lane>>1, k-half lane&1
  const __hip_bfloat16* gsrc = A + (size_t)(rbase + wave * 32 + (lane >> 1)) * K + (lane & 1) * 8;
  char* lb[2] = { &Atile[0][wave * 1024], &Atile[1][wave * 1024] };

  {  // stage iter 0
    const __hip_bfloat16* g = gsrc;
#pragma unroll
    for (int d = 0; d < 8; ++d) load_lds16(g + d * 16, lb[0] + d * 4096);
  }

  const __hip_bfloat16* wbase = Wpk + ((size_t)(cw * 4) * S * 64 + lane) * 8;
  const int aoff = (lane & 31) * 32 + (lane >> 5) * 16;
  f32x16 acc[2][4] = {};

  for (int kb = 0; kb < NIT; ++kb) {
    __syncthreads();  // drains DMAs for buf[kb&1]; prev readers of other buf done
    if (kb + 1 < NIT) {
      const __hip_bfloat16* g = gsrc + (size_t)(kb + 1) * 128;
      char* l = lb[(kb + 1) & 1];
#pragma unroll
      for (int d = 0; d < 8; ++d) load_lds16(g + d * 16, l + d * 4096);
    }
    const char* ab = Atile[kb & 1];
#pragma unroll
    for (int s = 0; s < 8; ++s) {
      const int ks = kb * 8 + s;
      const bf16x8 a0 = *(const bf16x8*)(ab + (s * 4 + rw * 2 + 0) * 1024 + aoff);
      const bf16x8 a1 = *(const bf16x8*)(ab + (s * 4 + rw * 2 + 1) * 1024 + aoff);
      const bf16x8 w0 = *(const bf16x8*)(wbase + ((size_t)0 * S + ks) * 512);
      const bf16x8 w1 = *(const bf16x8*)(wbase + ((size_t)1 * S + ks) * 512);
      const bf16x8 w2 = *(const bf16x8*)(wbase + ((size_t)2 * S + ks) * 512);
      const bf16x8 w3 = *(const bf16x8*)(wbase + ((size_t)3 * S + ks) * 512);
      acc[0][0] = __builtin_amdgcn_mfma_f32_32x32x16_bf16(a0, w0, acc[0][0], 0, 0, 0);
      acc[0][1] = __builtin_amdgcn_mfma_f32_32x32x16_bf16(a0, w1, acc[0][1], 0, 0, 0);
      acc[0][2] = __builtin_amdgcn_mfma_f32_32x32x16_bf16(a0, w2, acc[0][2], 0, 0, 0);
      acc[0][3] = __builtin_amdgcn_mfma_f32_32x32x16_bf16(a0, w3, acc[0][3], 0, 0, 0);
      acc[1][0] = __builtin_amdgcn_mfma_f32_32x32x16_bf16(a1, w0, acc[1][0], 0, 0, 0);
      acc[1][1] = __builtin_amdgcn_mfma_f32_32x32x16_bf16(a1, w1, acc[1][1], 0, 0, 0);
      acc[1][2] = __builtin_amdgcn_mfma_f32_32x32x16_bf16(a1, w2, acc[1][2], 0, 0, 0);
      acc[1][3] = __builtin_amdgcn_mfma_f32_32x32x16_bf16(a1, w3, acc[1][3], 0, 0, 0);
    }
  }

#pragma unroll
  for (int rh = 0; rh < 2; ++rh) {
#pragma unroll
    for (int t = 0; t < 4; ++t) {
      const int col = cw * 128 + t * 32 + (lane & 31);
      const float bj = bias[col];
      float ls = 0.f, ls2 = 0.f, lmax = -INFINITY, lmin = INFINITY;
#pragma unroll
      for (int r = 0; r < 16; ++r) {
        const int row = rbase + rw * 64 + rh * 32 + (r & 3) + 8 * (r >> 2) + 4 * (lane >> 5);
        if (row < M) {
          float v = acc[rh][t][r] + bj;
          if (STORE) Cb[(size_t)row * 768 + 512 + col] = __float2bfloat16(v);
          ls += v;
          ls2 = fmaf(v, v, ls2);
          lmax = fmaxf(lmax, v);
          lmin = fminf(lmin, v);
        }
      }
      atomicAdd(&colsum[col], ls);
      atomicAdd(&colsum2[col], ls2);
      atomicMax(&cmax[col], fkey(lmax));
      atomicMax(&cmin[col], ~fkey(lmin));
    }
  }
  __syncthreads();
  atomicAdd(&bnsum[threadIdx.x], colsum[threadIdx.x]);
  atomicAdd(&bnsum2[threadIdx.x], colsum2[threadIdx.x]);
  atomicMax(&gmax[threadIdx.x], cmax[threadIdx.x]);
  atomicMax(&gmin[threadIdx.x], cmin[threadIdx.x]);
}

// ---------- BN+ReLU in place on A2 self-slice (bf16 -> bf16) ----------
__global__ void bn_apply_kernel(__hip_bfloat16* __restrict__ A2,
                                const float* __restrict__ sum, const float* __restrict__ sumsq,
                                const float* __restrict__ gamma, const float* __restrict__ beta,
                                int n_nodes, float inv_n) {
  int j = threadIdx.x;
  float mu = sum[j] * inv_n;
  float rs = rsqrtf(fmaxf(sumsq[j] * inv_n - mu * mu, 0.f) + BN_EPS);
  float g = gamma[j] * rs, b = fmaf(-mu, g, beta[j]);
  for (int row = blockIdx.x; row < n_nodes; row += gridDim.x) {
    size_t idx = (size_t)row * 768 + 512 + j;
    float v = __bfloat162float(A2[idx]);
    v = fmaxf(fmaf(v, g, b), 0.f);
    A2[idx] = __float2bfloat16(v);
  }
}

// ---------- finalize: out[j] from fused layer-2 stats (monotone max/min trick) ----------
__global__ void finalize_kernel(const unsigned* __restrict__ xw,
                                const float* __restrict__ sum, const float* __restrict__ sumsq,
                                const unsigned* __restrict__ gmax, const unsigned* __restrict__ gmin,
                                const float* __restrict__ gamma, const float* __restrict__ beta,
                                float inv_n, void* __restrict__ out, int out_size) {
  __shared__ int votes;
  if (threadIdx.x == 0) votes = 0;
  __syncthreads();
  unsigned e = (xw[threadIdx.x] >> 7) & 0xFFu;
  if (e >= 100u && e <= 140u) atomicAdd(&votes, 1);
  __syncthreads();
  int bf = votes > 128;
  int j = threadIdx.x;
  if (j >= out_size) return;
  float mu = sum[j] * inv_n;
  float rs = rsqrtf(fmaxf(sumsq[j] * inv_n - mu * mu, 0.f) + BN_EPS);
  float g = gamma[j] * rs, b = fmaf(-mu, g, beta[j]);
  float vmax = finv(gmax[j]);
  float vmin = finv(~gmin[j]);
  float v = fmaxf(fmaf(g, (g >= 0.f) ? vmax : vmin, b), 0.f);
  if (bf) ((__hip_bfloat16*)out)[j] = __float2bfloat16(v);
  else    ((float*)out)[j] = v;
}

extern "C" void kernel_launch(void* const* d_in, const int* in_sizes, int n_in,
                              void* d_out, int out_size, void* d_ws, size_t ws_size,
                              hipStream_t stream) {
  const void* x  = d_in[0];
  const void* ei = d_in[1];
  const int n_nodes = in_sizes[0] / IN_DIM;
  const int n_edges = in_sizes[1] / 2;
  const int nb = (n_nodes + 255) / 256;
  const int Mpad = (n_nodes + 127) & ~127;  // 128-row GEMM tiles

  float* ws = (float*)d_ws;
  size_t off = 0;
  auto alloc = [&](size_t n) {
    float* p = ws + off;
    off += (n + 1023) & ~(size_t)1023;
    return p;
  };
  __hip_bfloat16* Wpk1 = (__hip_bfloat16*)alloc(384 * 256 / 2);
  __hip_bfloat16* Wpk2 = (__hip_bfloat16*)alloc(768 * 256 / 2);
  float* b1      = alloc(256);
  float* b2      = alloc(256);
  float* gamma1  = alloc(256);
  float* beta1   = alloc(256);
  float* gamma2  = alloc(256);
  float* beta2   = alloc(256);
  // contiguous zero region: degf | degb | sums/keys
  float* zeros   = alloc(2 * (size_t)n_nodes + 2048);
  int*   degf    = (int*)zeros;
  int*   degb    = degf + n_nodes;
  float* sum1    = zeros + 2 * (size_t)n_nodes;
  float* sumsq1  = sum1 + 256;
  float* sum2    = sum1 + 512;
  float* sumsq2  = sum1 + 768;
  unsigned* max1 = (unsigned*)(sum1 + 1024);
  unsigned* min1 = (unsigned*)(sum1 + 1280);
  unsigned* max2 = (unsigned*)(sum1 + 1536);
  unsigned* min2 = (unsigned*)(sum1 + 1792);
  int*   srcI    = (int*)alloc(n_edges);
  int*   dstI    = (int*)alloc(n_edges);
  int*   offf    = (int*)alloc(n_nodes + 1);
  int*   offb    = (int*)alloc(n_nodes + 1);
  int*   curf    = (int*)alloc(n_nodes);
  int*   curb    = (int*)alloc(n_nodes);
  int*   adjf    = (int*)alloc(n_edges);
  int*   adjb    = (int*)alloc(n_edges);
  int*   partials = (int*)alloc(2 * nb);
  __hip_bfloat16* A1 = (__hip_bfloat16*)alloc((size_t)Mpad * 384 / 2);
  __hip_bfloat16* A2 = (__hip_bfloat16*)alloc((size_t)Mpad * 768 / 2);
  (void)ws_size; (void)n_in;

  hipMemsetAsync(zeros, 0, (2 * (size_t)n_nodes + 2048) * 4, stream);

  const int pgrid = (n_edges + 255) / 256;
  prep_kernel<<<pgrid, 256, 0, stream>>>(
      x, ei,
      d_in[2], d_in[3], d_in[4], d_in[5], d_in[6], d_in[7],
      d_in[8], d_in[9], d_in[10], d_in[11], d_in[12], d_in[13],
      d_in[14], d_in[15], d_in[16], d_in[17],
      srcI, dstI, degf, degb, A1,
      Wpk1, b1, Wpk2, b2, gamma1, beta1, gamma2, beta2, n_nodes, n_edges);

  scan_part_kernel<<<2 * nb, 256, 0, stream>>>(degf, degb, offf, offb, partials, n_nodes, nb);
  scan_partials_kernel<<<1, 256, 0, stream>>>(partials, nb);
  scan_add_kernel<<<2 * nb, 256, 0, stream>>>(offf, offb, curf, curb, partials, n_nodes, nb, n_edges);
  fill_adj_kernel<<<(n_edges + 255) / 256, 256, 0, stream>>>(srcI, dstI, curf, curb, adjf, adjb, n_edges);

  const float inv_n = 1.0f / (float)n_nodes;
  const int gemm_grid = Mpad / 128;

  // ---- layer 1 ----
  gather_mean_kernel<IN_DIM><<<(2 * n_nodes + 3) / 4, 256, 0, stream>>>(
      A1, adjf, offf, adjb, offb, n_nodes);
  gemm_mfma_kernel<384, true><<<gemm_grid, 256, 0, stream>>>(
      A1, Wpk1, b1, A2, sum1, sumsq1, max1, min1, n_nodes);
  bn_apply_kernel<<<1024, 256, 0, stream>>>(A2, sum1, sumsq1, gamma1, beta1, n_nodes, inv_n);

  // ---- layer 2 (no C store; stats + max/min fused) ----
  gather_mean_kernel<HID><<<(2 * n_nodes + 3) / 4, 256, 0, stream>>>(
      A2, adjf, offf, adjb, offb, n_nodes);
  gemm_mfma_kernel<768, false><<<gemm_grid, 256, 0, stream>>>(
      A2, Wpk2, b2, nullptr, sum2, sumsq2, max2, min2, n_nodes);
  finalize_kernel<<<1, 256, 0, stream>>>(
      (const unsigned*)x, sum2, sumsq2, max2, min2, gamma2, beta2, inv_n, d_out, out_size);
}

// Round 9
// 380.244 us; speedup vs baseline: 1.4668x; 1.0606x over previous
//
#include <hip/hip_runtime.h>
#include <hip/hip_bf16.h>

#define IN_DIM 128
#define HID 256
#define BN_EPS 1e-5f

typedef __attribute__((ext_vector_type(8))) short bf16x8;
typedef __attribute__((ext_vector_type(16))) float f32x16;

// ---------- helpers ----------
__device__ __forceinline__ float ld_f(const void* p, size_t i, int bf16) {
  if (bf16) return __bfloat162float(((const __hip_bfloat16*)p)[i]);
  return ((const float*)p)[i];
}
__device__ __forceinline__ float blo(unsigned u) { return __uint_as_float(u << 16); }
__device__ __forceinline__ float bhi(unsigned u) { return __uint_as_float(u & 0xffff0000u); }
__device__ __forceinline__ unsigned short f2bf(float f) {
  __hip_bfloat16 b = __float2bfloat16(f);
  return __builtin_bit_cast(unsigned short, b);
}
__device__ __forceinline__ void load_lds16(const void* g, void* l) {
  __builtin_amdgcn_global_load_lds((const __attribute__((address_space(1))) void*)g,
                                   (__attribute__((address_space(3))) void*)l, 16, 0, 0);
}
// order-preserving float->uint key (monotone increasing); init 0 is neutral for max
__device__ __forceinline__ unsigned fkey(float v) {
  unsigned s = __float_as_uint(v);
  return (s & 0x80000000u) ? ~s : (s | 0x80000000u);
}
__device__ __forceinline__ float finv(unsigned k) {
  unsigned s = (k & 0x80000000u) ? (k ^ 0x80000000u) : ~k;
  return __uint_as_float(s);
}

// ---------- mega prep: flag detect (per block) + histogram + x->A1 + W packs ----------
__global__ void prep_kernel(
    const void* __restrict__ x, const void* __restrict__ ei,
    const void* Wl_f1, const void* bl_f1, const void* Wr_f1,
    const void* Wl_b1, const void* bl_b1, const void* Wr_b1,
    const void* Wl_f2, const void* bl_f2, const void* Wr_f2,
    const void* Wl_b2, const void* bl_b2, const void* Wr_b2,
    const void* g1, const void* be1, const void* g2, const void* be2,
    int* __restrict__ degf, int* __restrict__ degb,
    __hip_bfloat16* __restrict__ A1,
    __hip_bfloat16* __restrict__ Wpk1, float* __restrict__ b1,
    __hip_bfloat16* __restrict__ Wpk2, float* __restrict__ b2,
    float* __restrict__ gamma1, float* __restrict__ beta1,
    float* __restrict__ gamma2, float* __restrict__ beta2,
    int n_nodes, int n_edges) {
  __shared__ int votes, nz;
  if (threadIdx.x == 0) { votes = 0; nz = 0; }
  __syncthreads();
  {
    unsigned e = (((const unsigned*)x)[threadIdx.x] >> 7) & 0xFFu;
    if (e >= 100u && e <= 140u) atomicAdd(&votes, 1);
    if (((const unsigned*)ei)[2 * threadIdx.x + 1] != 0u) atomicAdd(&nz, 1);
  }
  __syncthreads();
  const int bf = (votes > 128) ? 1 : 0;
  const int i32 = (nz > 0) ? 1 : 0;
  const int tid = blockIdx.x * 256 + threadIdx.x;
  const int nt = gridDim.x * 256;
  // degree histogram (degf by dst, degb by src)
  for (int i = tid; i < n_edges; i += nt) {
    int s, d;
    if (i32) { s = ((const int*)ei)[i]; d = ((const int*)ei)[n_edges + i]; }
    else     { s = (int)((const long long*)ei)[i]; d = (int)((const long long*)ei)[n_edges + i]; }
    atomicAdd(&degf[d], 1);
    atomicAdd(&degb[s], 1);
  }
  // x -> bf16 self-slice of A1 (cols 256..383, row stride 384), 4 elems/thread-iter
  const size_t nq = (size_t)n_nodes * IN_DIM / 4;
  for (size_t q = tid; q < nq; q += nt) {
    const int row = (int)(q >> 5), j = (int)(q & 31) * 4;
    __hip_bfloat16* dstp = A1 + (size_t)row * 384 + 256 + j;
    if (bf) {
      *(uint2*)dstp = ((const uint2*)x)[q];
    } else {
      float4 v = ((const float4*)x)[q];
      unsigned short o[4] = {f2bf(v.x), f2bf(v.y), f2bf(v.z), f2bf(v.w)};
      *(uint2*)dstp = *(uint2*)o;
    }
  }
  // W packs (MFMA B-frag order) + biases/BN params
  for (int idx = tid; idx < 768 * 256; idx += nt) {
    {
      int j = idx & 7, l = (idx >> 3) & 63, rest = idx >> 9;
      int s = rest % 48, t = rest / 48;
      int k = s * 16 + (l >> 5) * 8 + j, col = t * 32 + (l & 31);
      float v;
      if (k < 256)      v = ld_f(Wl_f2, (size_t)k * 256 + col, bf);
      else if (k < 512) v = ld_f(Wl_b2, (size_t)(k - 256) * 256 + col, bf);
      else              v = ld_f(Wr_f2, (size_t)(k - 512) * 256 + col, bf) +
                            ld_f(Wr_b2, (size_t)(k - 512) * 256 + col, bf);
      Wpk2[idx] = __float2bfloat16(v);
    }
    if (idx < 384 * 256) {
      int j = idx & 7, l = (idx >> 3) & 63, rest = idx >> 9;
      int s = rest % 24, t = rest / 24;
      int k = s * 16 + (l >> 5) * 8 + j, col = t * 32 + (l & 31);
      float v;
      if (k < 128)      v = ld_f(Wl_f1, (size_t)k * 256 + col, bf);
      else if (k < 256) v = ld_f(Wl_b1, (size_t)(k - 128) * 256 + col, bf);
      else              v = ld_f(Wr_f1, (size_t)(k - 256) * 256 + col, bf) +
                            ld_f(Wr_b1, (size_t)(k - 256) * 256 + col, bf);
      Wpk1[idx] = __float2bfloat16(v);
    }
    if (idx < 256) {
      b1[idx] = ld_f(bl_f1, idx, bf) + ld_f(bl_b1, idx, bf);
      b2[idx] = ld_f(bl_f2, idx, bf) + ld_f(bl_b2, idx, bf);
      gamma1[idx] = ld_f(g1, idx, bf);
      beta1[idx]  = ld_f(be1, idx, bf);
      gamma2[idx] = ld_f(g2, idx, bf);
      beta2[idx]  = ld_f(be2, idx, bf);
    }
  }
}

// ---------- CSR build ----------
__global__ void scan_part_kernel(const int* __restrict__ degf, const int* __restrict__ degb,
                                 int* __restrict__ offf, int* __restrict__ offb,
                                 int* __restrict__ partials, int n, int nb) {
  __shared__ int buf[256];
  const int b = blockIdx.x;
  const int* deg = (b < nb) ? degf : degb;
  int* off = (b < nb) ? offf : offb;
  const int chunk = (b < nb) ? b : (b - nb);
  const int i = chunk * 256 + threadIdx.x;
  int v = (i < n) ? deg[i] : 0;
  buf[threadIdx.x] = v;
  __syncthreads();
  for (int s = 1; s < 256; s <<= 1) {
    int t = (threadIdx.x >= s) ? buf[threadIdx.x - s] : 0;
    __syncthreads();
    buf[threadIdx.x] += t;
    __syncthreads();
  }
  if (i < n) off[i] = buf[threadIdx.x] - v;
  if (threadIdx.x == 255) partials[b] = buf[255];
}

// merged: each block reduces its own prefix over partials (nb <= 256) then adds
__global__ void scan_add_kernel(int* __restrict__ offf, int* __restrict__ offb,
                                int* __restrict__ curf, int* __restrict__ curb,
                                const int* __restrict__ partials, int n, int nb, int n_edges) {
  __shared__ int red[256];
  const int b = blockIdx.x;
  int* off = (b < nb) ? offf : offb;
  int* cur = (b < nb) ? curf : curb;
  const int chunk = (b < nb) ? b : (b - nb);
  const int abase = (b < nb) ? 0 : nb;
  int v = (threadIdx.x < chunk) ? partials[abase + threadIdx.x] : 0;
  red[threadIdx.x] = v;
  __syncthreads();
  for (int s = 128; s > 0; s >>= 1) {
    if (threadIdx.x < s) red[threadIdx.x] += red[threadIdx.x + s];
    __syncthreads();
  }
  const int prefix = red[0];
  const int i = chunk * 256 + threadIdx.x;
  if (i < n) {
    int t = off[i] + prefix;
    off[i] = t;
    cur[i] = t;
  }
  if (b == 0 && threadIdx.x == 0) { offf[n] = n_edges; offb[n] = n_edges; }
}

// decodes edge_index directly (per-block int64 vote)
__global__ void fill_adj_kernel(const void* __restrict__ ei,
                                int* __restrict__ curf, int* __restrict__ curb,
                                int* __restrict__ adjf, int* __restrict__ adjb, int n_edges) {
  __shared__ int nz;
  if (threadIdx.x == 0) nz = 0;
  __syncthreads();
  if (((const unsigned*)ei)[2 * threadIdx.x + 1] != 0u) atomicAdd(&nz, 1);
  __syncthreads();
  const int i32 = nz > 0;
  int i = blockIdx.x * 256 + threadIdx.x;
  if (i >= n_edges) return;
  int s, d;
  if (i32) { s = ((const int*)ei)[i]; d = ((const int*)ei)[n_edges + i]; }
  else     { s = (int)((const long long*)ei)[i]; d = (int)((const long long*)ei)[n_edges + i]; }
  adjf[atomicAdd(&curf[d], 1)] = s;
  adjb[atomicAdd(&curb[s], 1)] = d;
}

// ---------- gather-mean v3: unroll x2, 4 rows + 2 idx in flight ----------
template <int D>
__global__ __launch_bounds__(256) void gather_mean_kernel(
    __hip_bfloat16* __restrict__ A,
    const int* __restrict__ adjf, const int* __restrict__ offf,
    const int* __restrict__ adjb, const int* __restrict__ offb, int n_nodes) {
  constexpr int LPN = D / 8;
  constexpr int NPI = 64 / LPN;
  const int gw = (int)(((size_t)blockIdx.x * 256 + threadIdx.x) >> 6);
  const int lane = threadIdx.x & 63;
  if (gw >= 2 * n_nodes) return;
  int node, dir;
  const int *adj, *off;
  if (gw < n_nodes) { node = gw;           adj = adjf; off = offf; dir = 0; }
  else              { node = gw - n_nodes; adj = adjb; off = offb; dir = 1; }
  const int s = off[node], e = off[node + 1];
  const int sub = lane / LPN, cl = lane % LPN;
  const size_t coloff = 2 * (size_t)D + cl * 8;
  auto clampi = [&](int i) { return max(min(i, e - 1), 0); };
  auto ROW = [&](int a) { return *(const uint4*)(A + (size_t)a * (3 * D) + coloff); };
  float acc[8] = {0.f, 0.f, 0.f, 0.f, 0.f, 0.f, 0.f, 0.f};
  int i = s + sub;
  int a0 = adj[clampi(i)];
  int a1 = adj[clampi(i + NPI)];
  int a2 = adj[clampi(i + 2 * NPI)];
  int a3 = adj[clampi(i + 3 * NPI)];
  uint4 r0 = ROW(a0);
  uint4 r1 = ROW(a1);
  for (; i < e; i += 2 * NPI) {
    const uint4 r2 = ROW(a2), r3 = ROW(a3);  // next pair in flight
    const int a4 = adj[clampi(i + 4 * NPI)];
    const int a5 = adj[clampi(i + 5 * NPI)];
    acc[0] += blo(r0.x); acc[1] += bhi(r0.x);
    acc[2] += blo(r0.y); acc[3] += bhi(r0.y);
    acc[4] += blo(r0.z); acc[5] += bhi(r0.z);
    acc[6] += blo(r0.w); acc[7] += bhi(r0.w);
    if (i + NPI < e) {
      acc[0] += blo(r1.x); acc[1] += bhi(r1.x);
      acc[2] += blo(r1.y); acc[3] += bhi(r1.y);
      acc[4] += blo(r1.z); acc[5] += bhi(r1.z);
      acc[6] += blo(r1.w); acc[7] += bhi(r1.w);
    }
    r0 = r2; r1 = r3; a2 = a4; a3 = a5;
  }
#pragma unroll
  for (int o = 32; o >= LPN; o >>= 1) {
#pragma unroll
    for (int k = 0; k < 8; ++k) acc[k] += __shfl_xor(acc[k], o, 64);
  }
  if (sub == 0) {
    const float inv = 1.0f / (float)max(e - s, 1);
    union { unsigned short us[8]; uint4 v; } o;
#pragma unroll
    for (int k = 0; k < 8; ++k) o.us[k] = f2bf(acc[k] * inv);
    *(uint4*)(A + (size_t)node * (3 * D) + dir * D + cl * 8) = o.v;
  }
}

// ---------- MFMA GEMM v6: 128 rows x 256 cols / block, BK=128 double-buffered LDS ----------
template <int K, bool STORE>
__global__ __launch_bounds__(256, 2) void gemm_mfma_kernel(
    const __hip_bfloat16* __restrict__ A, const __hip_bfloat16* __restrict__ Wpk,
    const float* __restrict__ bias, __hip_bfloat16* __restrict__ Cb,
    float* __restrict__ bnsum, float* __restrict__ bnsum2,
    unsigned* __restrict__ gmax, unsigned* __restrict__ gmin, int M) {
  constexpr int S = K / 16;    // total k-steps
  constexpr int NIT = K / 128; // BK=128 iterations
  __shared__ __align__(16) char Atile[2][32768];
  __shared__ float colsum[256], colsum2[256];
  __shared__ unsigned cmax[256], cmin[256];
  colsum[threadIdx.x] = 0.f; colsum2[threadIdx.x] = 0.f;
  cmax[threadIdx.x] = 0u; cmin[threadIdx.x] = 0u;
  const int wave = threadIdx.x >> 6, lane = threadIdx.x & 63;
  const int rw = wave >> 1, cw = wave & 1;
  const int rbase = blockIdx.x * 128;
  const __hip_bfloat16* gsrc = A + (size_t)(rbase + wave * 32 + (lane >> 1)) * K + (lane & 1) * 8;
  char* lb[2] = { &Atile[0][wave * 1024], &Atile[1][wave * 1024] };

  {
    const __hip_bfloat16* g = gsrc;
#pragma unroll
    for (int d = 0; d < 8; ++d) load_lds16(g + d * 16, lb[0] + d * 4096);
  }

  const __hip_bfloat16* wbase = Wpk + ((size_t)(cw * 4) * S * 64 + lane) * 8;
  const int aoff = (lane & 31) * 32 + (lane >> 5) * 16;
  f32x16 acc[2][4] = {};

  for (int kb = 0; kb < NIT; ++kb) {
    __syncthreads();
    if (kb + 1 < NIT) {
      const __hip_bfloat16* g = gsrc + (size_t)(kb + 1) * 128;
      char* l = lb[(kb + 1) & 1];
#pragma unroll
      for (int d = 0; d < 8; ++d) load_lds16(g + d * 16, l + d * 4096);
    }
    const char* ab = Atile[kb & 1];
#pragma unroll
    for (int s = 0; s < 8; ++s) {
      const int ks = kb * 8 + s;
      const bf16x8 a0 = *(const bf16x8*)(ab + (s * 4 + rw * 2 + 0) * 1024 + aoff);
      const bf16x8 a1 = *(const bf16x8*)(ab + (s * 4 + rw * 2 + 1) * 1024 + aoff);
      const bf16x8 w0 = *(const bf16x8*)(wbase + ((size_t)0 * S + ks) * 512);
      const bf16x8 w1 = *(const bf16x8*)(wbase + ((size_t)1 * S + ks) * 512);
      const bf16x8 w2 = *(const bf16x8*)(wbase + ((size_t)2 * S + ks) * 512);
      const bf16x8 w3 = *(const bf16x8*)(wbase + ((size_t)3 * S + ks) * 512);
      acc[0][0] = __builtin_amdgcn_mfma_f32_32x32x16_bf16(a0, w0, acc[0][0], 0, 0, 0);
      acc[0][1] = __builtin_amdgcn_mfma_f32_32x32x16_bf16(a0, w1, acc[0][1], 0, 0, 0);
      acc[0][2] = __builtin_amdgcn_mfma_f32_32x32x16_bf16(a0, w2, acc[0][2], 0, 0, 0);
      acc[0][3] = __builtin_amdgcn_mfma_f32_32x32x16_bf16(a0, w3, acc[0][3], 0, 0, 0);
      acc[1][0] = __builtin_amdgcn_mfma_f32_32x32x16_bf16(a1, w0, acc[1][0], 0, 0, 0);
      acc[1][1] = __builtin_amdgcn_mfma_f32_32x32x16_bf16(a1, w1, acc[1][1], 0, 0, 0);
      acc[1][2] = __builtin_amdgcn_mfma_f32_32x32x16_bf16(a1, w2, acc[1][2], 0, 0, 0);
      acc[1][3] = __builtin_amdgcn_mfma_f32_32x32x16_bf16(a1, w3, acc[1][3], 0, 0, 0);
    }
  }

#pragma unroll
  for (int rh = 0; rh < 2; ++rh) {
#pragma unroll
    for (int t = 0; t < 4; ++t) {
      const int col = cw * 128 + t * 32 + (lane & 31);
      const float bj = bias[col];
      float ls = 0.f, ls2 = 0.f, lmax = -INFINITY, lmin = INFINITY;
#pragma unroll
      for (int r = 0; r < 16; ++r) {
        const int row = rbase + rw * 64 + rh * 32 + (r & 3) + 8 * (r >> 2) + 4 * (lane >> 5);
        if (row < M) {
          float v = acc[rh][t][r] + bj;
          if (STORE) Cb[(size_t)row * 768 + 512 + col] = __float2bfloat16(v);
          ls += v;
          ls2 = fmaf(v, v, ls2);
          lmax = fmaxf(lmax, v);
          lmin = fminf(lmin, v);
        }
      }
      atomicAdd(&colsum[col], ls);
      atomicAdd(&colsum2[col], ls2);
      atomicMax(&cmax[col], fkey(lmax));
      atomicMax(&cmin[col], ~fkey(lmin));
    }
  }
  __syncthreads();
  atomicAdd(&bnsum[threadIdx.x], colsum[threadIdx.x]);
  atomicAdd(&bnsum2[threadIdx.x], colsum2[threadIdx.x]);
  atomicMax(&gmax[threadIdx.x], cmax[threadIdx.x]);
  atomicMax(&gmin[threadIdx.x], cmin[threadIdx.x]);
}

// ---------- BN+ReLU in place on A2 self-slice (bf16 -> bf16) ----------
__global__ void bn_apply_kernel(__hip_bfloat16* __restrict__ A2,
                                const float* __restrict__ sum, const float* __restrict__ sumsq,
                                const float* __restrict__ gamma, const float* __restrict__ beta,
                                int n_nodes, float inv_n) {
  int j = threadIdx.x;
  float mu = sum[j] * inv_n;
  float rs = rsqrtf(fmaxf(sumsq[j] * inv_n - mu * mu, 0.f) + BN_EPS);
  float g = gamma[j] * rs, b = fmaf(-mu, g, beta[j]);
  for (int row = blockIdx.x; row < n_nodes; row += gridDim.x) {
    size_t idx = (size_t)row * 768 + 512 + j;
    float v = __bfloat162float(A2[idx]);
    v = fmaxf(fmaf(v, g, b), 0.f);
    A2[idx] = __float2bfloat16(v);
  }
}

// ---------- finalize: out[j] from fused layer-2 stats (monotone max/min trick) ----------
__global__ void finalize_kernel(const unsigned* __restrict__ xw,
                                const float* __restrict__ sum, const float* __restrict__ sumsq,
                                const unsigned* __restrict__ gmax, const unsigned* __restrict__ gmin,
                                const float* __restrict__ gamma, const float* __restrict__ beta,
                                float inv_n, void* __restrict__ out, int out_size) {
  __shared__ int votes;
  if (threadIdx.x == 0) votes = 0;
  __syncthreads();
  unsigned e = (xw[threadIdx.x] >> 7) & 0xFFu;
  if (e >= 100u && e <= 140u) atomicAdd(&votes, 1);
  __syncthreads();
  int bf = votes > 128;
  int j = threadIdx.x;
  if (j >= out_size) return;
  float mu = sum[j] * inv_n;
  float rs = rsqrtf(fmaxf(sumsq[j] * inv_n - mu * mu, 0.f) + BN_EPS);
  float g = gamma[j] * rs, b = fmaf(-mu, g, beta[j]);
  float vmax = finv(gmax[j]);
  float vmin = finv(~gmin[j]);
  float v = fmaxf(fmaf(g, (g >= 0.f) ? vmax : vmin, b), 0.f);
  if (bf) ((__hip_bfloat16*)out)[j] = __float2bfloat16(v);
  else    ((float*)out)[j] = v;
}

extern "C" void kernel_launch(void* const* d_in, const int* in_sizes, int n_in,
                              void* d_out, int out_size, void* d_ws, size_t ws_size,
                              hipStream_t stream) {
  const void* x  = d_in[0];
  const void* ei = d_in[1];
  const int n_nodes = in_sizes[0] / IN_DIM;
  const int n_edges = in_sizes[1] / 2;
  const int nb = (n_nodes + 255) / 256;
  const int Mpad = (n_nodes + 127) & ~127;

  float* ws = (float*)d_ws;
  size_t off = 0;
  auto alloc = [&](size_t n) {
    float* p = ws + off;
    off += (n + 1023) & ~(size_t)1023;
    return p;
  };
  __hip_bfloat16* Wpk1 = (__hip_bfloat16*)alloc(384 * 256 / 2);
  __hip_bfloat16* Wpk2 = (__hip_bfloat16*)alloc(768 * 256 / 2);
  float* b1      = alloc(256);
  float* b2      = alloc(256);
  float* gamma1  = alloc(256);
  float* beta1   = alloc(256);
  float* gamma2  = alloc(256);
  float* beta2   = alloc(256);
  float* zeros   = alloc(2 * (size_t)n_nodes + 2048);
  int*   degf    = (int*)zeros;
  int*   degb    = degf + n_nodes;
  float* sum1    = zeros + 2 * (size_t)n_nodes;
  float* sumsq1  = sum1 + 256;
  float* sum2    = sum1 + 512;
  float* sumsq2  = sum1 + 768;
  unsigned* max1 = (unsigned*)(sum1 + 1024);
  unsigned* min1 = (unsigned*)(sum1 + 1280);
  unsigned* max2 = (unsigned*)(sum1 + 1536);
  unsigned* min2 = (unsigned*)(sum1 + 1792);
  int*   offf    = (int*)alloc(n_nodes + 1);
  int*   offb    = (int*)alloc(n_nodes + 1);
  int*   curf    = (int*)alloc(n_nodes);
  int*   curb    = (int*)alloc(n_nodes);
  int*   adjf    = (int*)alloc(n_edges);
  int*   adjb    = (int*)alloc(n_edges);
  int*   partials = (int*)alloc(2 * nb);
  __hip_bfloat16* A1 = (__hip_bfloat16*)alloc((size_t)Mpad * 384 / 2);
  __hip_bfloat16* A2 = (__hip_bfloat16*)alloc((size_t)Mpad * 768 / 2);
  (void)ws_size; (void)n_in;

  hipMemsetAsync(zeros, 0, (2 * (size_t)n_nodes + 2048) * 4, stream);

  const int pgrid = (n_edges + 255) / 256;
  prep_kernel<<<pgrid, 256, 0, stream>>>(
      x, ei,
      d_in[2], d_in[3], d_in[4], d_in[5], d_in[6], d_in[7],
      d_in[8], d_in[9], d_in[10], d_in[11], d_in[12], d_in[13],
      d_in[14], d_in[15], d_in[16], d_in[17],
      degf, degb, A1,
      Wpk1, b1, Wpk2, b2, gamma1, beta1, gamma2, beta2, n_nodes, n_edges);

  scan_part_kernel<<<2 * nb, 256, 0, stream>>>(degf, degb, offf, offb, partials, n_nodes, nb);
  scan_add_kernel<<<2 * nb, 256, 0, stream>>>(offf, offb, curf, curb, partials, n_nodes, nb, n_edges);
  fill_adj_kernel<<<(n_edges + 255) / 256, 256, 0, stream>>>(ei, curf, curb, adjf, adjb, n_edges);

  const float inv_n = 1.0f / (float)n_nodes;
  const int gemm_grid = Mpad / 128;

  // ---- layer 1 ----
  gather_mean_kernel<IN_DIM><<<(2 * n_nodes + 3) / 4, 256, 0, stream>>>(
      A1, adjf, offf, adjb, offb, n_nodes);
  gemm_mfma_kernel<384, true><<<gemm_grid, 256, 0, stream>>>(
      A1, Wpk1, b1, A2, sum1, sumsq1, max1, min1, n_nodes);
  bn_apply_kernel<<<1024, 256, 0, stream>>>(A2, sum1, sumsq1, gamma1, beta1, n_nodes, inv_n);

  // ---- layer 2 (no C store; stats + max/min fused) ----
  gather_mean_kernel<HID><<<(2 * n_nodes + 3) / 4, 256, 0, stream>>>(
      A2, adjf, offf, adjb, offb, n_nodes);
  gemm_mfma_kernel<768, false><<<gemm_grid, 256, 0, stream>>>(
      A2, Wpk2, b2, nullptr, sum2, sumsq2, max2, min2, n_nodes);
  finalize_kernel<<<1, 256, 0, stream>>>(
      (const unsigned*)x, sum2, sumsq2, max2, min2, gamma2, beta2, inv_n, d_out, out_size);
}